// Round 13
// baseline (661.533 us; speedup 1.0000x reference)
//
#include <hip/hip_runtime.h>
#include <hip/hip_bf16.h>
#include <hip/hip_fp16.h>

typedef long long i64;
typedef unsigned int u32;
typedef __attribute__((ext_vector_type(8))) short bf16x8;
typedef __attribute__((ext_vector_type(4))) float f32x4;

#define MFMA_BF16 __builtin_amdgcn_mfma_f32_16x16x32_bf16
#define VMCNT(n)  asm volatile("s_waitcnt vmcnt(" #n ")" ::: "memory")
#define LGKM0     asm volatile("s_waitcnt lgkmcnt(0)" ::: "memory")
#define SBAR      __builtin_amdgcn_s_barrier()
#define SCHED0    __builtin_amdgcn_sched_barrier(0)

__device__ __forceinline__ void glds16(const void* g, void* l){
    __builtin_amdgcn_global_load_lds((const __attribute__((address_space(1))) u32*)g,
                                     (__attribute__((address_space(3))) u32*)l, 16, 0, 0);
}
// fp32 -> bf16 hi (truncate) + bf16 lo (residual). a ~= hi + lo, |err| ~ 2^-16 |a|
__device__ __forceinline__ void split1(float x, ushort& h, ushort& l){
    unsigned b = __float_as_uint(x);
    h = (ushort)(b >> 16);
    float hf = __uint_as_float(b & 0xFFFF0000u);
    float lf = x - hf;
    l = (ushort)(__float_as_uint(lf) >> 16);
}
__device__ __forceinline__ float bfpair(ushort h, ushort l){
    return __uint_as_float((u32)h << 16) + __uint_as_float((u32)l << 16);
}
// swizzled [64][64] bf16 tile read (flash staging): 16B-group g (0..7) XOR row&7
__device__ __forceinline__ bf16x8 fragS(const ushort* P, int row, int g){
    return *(const bf16x8*)&P[row*64 + (((g) ^ (row & 7)) << 3)];
}

struct P4 { const void* p[4]; };
struct I4 { int v[4]; };

// ---------------- pre-split: fp32 -> bf16 hi/lo planes ----------------
struct PSJobs { const float* s[13]; ushort* d[13]; int st[14]; };
__global__ __launch_bounds__(256) void presplit(PSJobs J){
    int bid = blockIdx.x, j = 0;
    while (bid >= J.st[j+1]) ++j;
    i64 base = (i64)(bid - J.st[j])*2048 + threadIdx.x*8;
    i64 loOff = (i64)(J.st[j+1] - J.st[j])*2048;
    const float* sp = J.s[j]; ushort* dp = J.d[j];
    float4 a = *(const float4*)&sp[base];
    float4 b = *(const float4*)&sp[base+4];
    float v[8] = {a.x,a.y,a.z,a.w,b.x,b.y,b.z,b.w};
    ushort h[8], l[8];
    #pragma unroll
    for (int t = 0; t < 8; ++t) split1(v[t], h[t], l[t]);
    *(ushort4*)&dp[base]         = make_ushort4(h[0],h[1],h[2],h[3]);
    *(ushort4*)&dp[base+4]       = make_ushort4(h[4],h[5],h[6],h[7]);
    *(ushort4*)&dp[loOff+base]   = make_ushort4(l[0],l[1],l[2],l[3]);
    *(ushort4*)&dp[loOff+base+4] = make_ushort4(l[4],l[5],l[6],l[7]);
}

// ---------------- TMx128-tile GEMM on pre-split planes, bf16x3, counted vmcnt ----
// C[m,n] = sum_k A[m,k]*B[n,k]; A/B k-contiguous bf16 hi planes (lo at +aLo/+bLo).
// TM=128: 2x2 waves, LDS 64KB (2 blocks/CU), vmcnt(8). TM=64: 1x4 waves, LDS
// 48KB (3 blocks/CU), vmcnt(6). OUT: 0 fp32; 1 planes (cfg=(tr<<30)|cld per z1);
// 2 fp16+stats; 3 KVS-scatter planes.
// Plain linear decode (x innermost, no XCD swizzle) -- round-6 measured best.
template<int TM, int OUT>
__global__ __launch_bounds__(256) void gemm_ps(
    P4 Ap, P4 Bp, P4 Cp, I4 cmode, float* __restrict__ stats,
    int K, int zdiv, int Y, int X,
    i64 ab2, i64 alda, i64 aLo,
    i64 bb2, i64 bldb, i64 bLo,
    i64 cb2, i64 cld, i64 cLo)
{
    constexpr int CW = (TM == 128) ? 64 : 32;
    constexpr int FJ = CW / 16;
    __shared__ ushort Ah[2][TM*32], Al[2][TM*32];
    __shared__ ushort Bh[2][4096], Bl[2][4096];
    __shared__ float sred[4], qred[4];
    int wg = blockIdx.x;
    const int x = wg % X;
    const int y = (wg / X) % Y;
    const int z = wg / (X * Y);
    const int z1 = z / zdiv, z2 = z % zdiv;
    const int m0 = y*TM, n0 = x*128;

    const int tid = threadIdx.x, lane = tid & 63, wid = tid >> 6;
    const int wm = (TM == 128) ? (wid >> 1) : 0;
    const int wn = (TM == 128) ? (wid & 1) : wid;
    const int fr = lane & 15, kc = lane >> 4;
    const ushort* Aps = (const ushort*)Ap.p[z1] + (i64)z2*ab2 + (i64)m0*alda;
    const ushort* Bps = (const ushort*)Bp.p[z1] + (i64)z2*bb2 + (i64)n0*bldb;

    auto stageAB = [&](int k0, int pb){
        if constexpr (TM == 128) {
            #pragma unroll
            for (int q = 0; q < 2; ++q) {
                int r  = wid*32 + (lane >> 2) + q*16;
                int gs = (lane & 3) ^ ((r >> 1) & 3);
                const ushort* sa = Aps + (i64)r*alda + k0 + gs*8;
                glds16(sa,       &Ah[pb][(wid*32+q*16)*32]);
                glds16(sa + aLo, &Al[pb][(wid*32+q*16)*32]);
            }
        } else {
            int r  = wid*16 + (lane >> 2);
            int gs = (lane & 3) ^ ((r >> 1) & 3);
            const ushort* sa = Aps + (i64)r*alda + k0 + gs*8;
            glds16(sa,       &Ah[pb][(wid*16)*32]);
            glds16(sa + aLo, &Al[pb][(wid*16)*32]);
        }
        #pragma unroll
        for (int q = 0; q < 2; ++q) {
            int r  = wid*32 + (lane >> 2) + q*16;
            int gs = (lane & 3) ^ ((r >> 1) & 3);
            const ushort* sb = Bps + (i64)r*bldb + k0 + gs*8;
            glds16(sb,       &Bh[pb][(wid*32+q*16)*32]);
            glds16(sb + bLo, &Bl[pb][(wid*32+q*16)*32]);
        }
    };
    auto rd = [&](const ushort* P, int row, int kcc)->bf16x8 {
        return *(const bf16x8*)&P[row*32 + ((kcc ^ ((row >> 1) & 3)) << 3)];
    };

    f32x4 acc[4][FJ];
    #pragma unroll
    for (int i = 0; i < 4; ++i)
        #pragma unroll
        for (int j = 0; j < FJ; ++j) acc[i][j] = (f32x4){0.f,0.f,0.f,0.f};

    const int NT = K >> 5;
    stageAB(0, 0); stageAB(32, 1);

    for (int t = 0; t < NT; ++t) {
        const int cur = t & 1;
        if (t + 1 < NT) {
            if constexpr (TM == 128) { VMCNT(8); } else { VMCNT(6); }
        } else { VMCNT(0); }
        SBAR;
        bf16x8 a_h[4], a_l[4], b_h[FJ], b_l[FJ];
        #pragma unroll
        for (int i = 0; i < 4; ++i) {
            int row = wm*64 + i*16 + fr;
            a_h[i] = rd(Ah[cur], row, kc);
            a_l[i] = rd(Al[cur], row, kc);
        }
        #pragma unroll
        for (int j = 0; j < FJ; ++j) {
            int row = wn*CW + j*16 + fr;
            b_h[j] = rd(Bh[cur], row, kc);
            b_l[j] = rd(Bl[cur], row, kc);
        }
        __builtin_amdgcn_s_setprio(1);
        #pragma unroll
        for (int i = 0; i < 4; ++i)
            #pragma unroll
            for (int j = 0; j < FJ; ++j) {
                acc[i][j] = MFMA_BF16(a_h[i], b_h[j], acc[i][j], 0, 0, 0);
                acc[i][j] = MFMA_BF16(a_h[i], b_l[j], acc[i][j], 0, 0, 0);
                acc[i][j] = MFMA_BF16(a_l[i], b_h[j], acc[i][j], 0, 0, 0);
            }
        __builtin_amdgcn_s_setprio(0);
        LGKM0;
        SBAR;
        SCHED0;
        if (t + 2 < NT) stageAB((t+2) << 5, cur);
    }

    const i64 cbase = (i64)z2*cb2;
    if (OUT == 0) {
        float* C = (float*)Cp.p[z1];
        #pragma unroll
        for (int i = 0; i < 4; ++i)
            #pragma unroll
            for (int j = 0; j < FJ; ++j)
                #pragma unroll
                for (int r = 0; r < 4; ++r) {
                    int m = m0 + wm*64 + i*16 + kc*4 + r;
                    int n = n0 + wn*CW + j*16 + fr;
                    C[cbase + (i64)m*cld + n] = acc[i][j][r];
                }
    } else if (OUT == 1) {
        ushort* C = (ushort*)Cp.p[z1];
        const int cfg = cmode.v[z1];
        const int tr = cfg >> 30;
        const i64 ldv = cfg & 0x3FFFFFFF;
        #pragma unroll
        for (int i = 0; i < 4; ++i)
            #pragma unroll
            for (int j = 0; j < FJ; ++j)
                #pragma unroll
                for (int r = 0; r < 4; ++r) {
                    int m = m0 + wm*64 + i*16 + kc*4 + r;
                    int n = n0 + wn*CW + j*16 + fr;
                    ushort h, l; split1(acc[i][j][r], h, l);
                    i64 off = cbase + (tr ? (i64)n*ldv + m : (i64)m*ldv + n);
                    C[off] = h; C[off + cLo] = l;
                }
    } else if (OUT == 2) {
        __half* C = (__half*)Cp.p[z1];
        float ls = 0.f, lq = 0.f;
        #pragma unroll
        for (int i = 0; i < 4; ++i)
            #pragma unroll
            for (int j = 0; j < FJ; ++j)
                #pragma unroll
                for (int r = 0; r < 4; ++r) {
                    int m = m0 + wm*64 + i*16 + kc*4 + r;
                    int n = n0 + wn*CW + j*16 + fr;
                    float v = acc[i][j][r];
                    ls += v; lq += v*v;
                    C[cbase + (i64)m*cld + n] = __float2half(v);
                }
        #pragma unroll
        for (int off = 32; off; off >>= 1) { ls += __shfl_xor(ls, off); lq += __shfl_xor(lq, off); }
        if (lane == 0) { sred[wid] = ls; qred[wid] = lq; }
        __syncthreads();
        if (tid == 0) {
            atomicAdd(&stats[2*z],   sred[0]+sred[1]+sred[2]+sred[3]);
            atomicAdd(&stats[2*z+1], qred[0]+qred[1]+qred[2]+qred[3]);
        }
    } else {
        ushort* C = (ushort*)Cp.p[z1];
        #pragma unroll
        for (int i = 0; i < 4; ++i)
            #pragma unroll
            for (int j = 0; j < FJ; ++j)
                #pragma unroll
                for (int r = 0; r < 4; ++r) {
                    int m = m0 + wm*64 + i*16 + kc*4 + r;
                    int n = n0 + wn*CW + j*16 + fr;
                    ushort h, l; split1(acc[i][j][r], h, l);
                    i64 off = cbase + ((i64)(m >> 9) << 18) + ((i64)n << 9) + (m & 511);
                    C[off] = h; C[off + cLo] = l;
                }
    }
}

// ---------------- channel softmax: fp16 scores in -> sim bf16 hi/lo planes out ----
__global__ __launch_bounds__(256) void softmax_rows(
    __half* __restrict__ attn, ushort* __restrict__ lo,
    const float* __restrict__ stats, int rows_per_stat, float inv_count)
{
    const int ROWLEN = 2048;
    const int row = blockIdx.x;
    const int sidx = row / rows_per_stat;
    float sm = stats[2*sidx], sq = stats[2*sidx+1];
    float mean = sm * inv_count;
    float var = fmaxf(sq * inv_count - mean*mean, 0.f);
    float scale = rsqrtf(var + 1e-5f);
    __half* rp = attn + (i64)row * ROWLEN;
    ushort* hp = (ushort*)rp;
    ushort* lp = lo + (i64)row * ROWLEN;
    const int tid = threadIdx.x;
    float v[8]; float mx = -3.4e38f;
    #pragma unroll
    for (int s = 0; s < 8; ++s) { float x = __half2float(rp[tid + s*256]) * scale; v[s] = x; mx = fmaxf(mx, x); }
    #pragma unroll
    for (int off = 32; off; off >>= 1) mx = fmaxf(mx, __shfl_xor(mx, off));
    __shared__ float red[4];
    if ((tid & 63) == 0) red[tid >> 6] = mx;
    __syncthreads();
    mx = fmaxf(fmaxf(red[0], red[1]), fmaxf(red[2], red[3]));
    float ls = 0.f;
    #pragma unroll
    for (int s = 0; s < 8; ++s) { float e = __expf(v[s] - mx); v[s] = e; ls += e; }
    #pragma unroll
    for (int off = 32; off; off >>= 1) ls += __shfl_xor(ls, off);
    __syncthreads();
    if ((tid & 63) == 0) red[tid >> 6] = ls;
    __syncthreads();
    float inv = 1.f / (red[0] + red[1] + red[2] + red[3]);
    #pragma unroll
    for (int s = 0; s < 8; ++s) {
        ushort h, l; split1(v[s] * inv, h, l);
        hp[tid + s*256] = h; lp[tid + s*256] = l;
    }
}

// ---------------- 64x64 Gram partials + column sums over 256 rows (planes input) ----------------
__global__ __launch_bounds__(256) void gram64(
    const ushort* __restrict__ hi, i64 loOff, float* __restrict__ parts,
    i64 bstride, i64 zs2)
{
    __shared__ float T[16][68];
    __shared__ float csred[4][64];
    const int z = blockIdx.x;
    const int tid = threadIdx.x;
    const ushort* base = hi + (i64)(z>>3)*bstride + (i64)blockIdx.z*zs2
                       + (i64)blockIdx.y*256*512 + (z&7)*64;
    float g[4][4] = {{0.f}};
    float cs = 0.f;
    const int sr = tid >> 4, sc = (tid & 15) * 4;
    const int col = tid & 63, qq = tid >> 6;
    for (int grp = 0; grp < 16; ++grp) {
        i64 idx = (i64)(grp*16 + sr)*512 + sc;
        ushort4 hv = *(const ushort4*)&base[idx];
        ushort4 lv = *(const ushort4*)&base[loOff + idx];
        float4 ld;
        ld.x = bfpair(hv.x, lv.x); ld.y = bfpair(hv.y, lv.y);
        ld.z = bfpair(hv.z, lv.z); ld.w = bfpair(hv.w, lv.w);
        __syncthreads();
        *(float4*)&T[sr][sc] = ld;
        __syncthreads();
        #pragma unroll
        for (int rr = 0; rr < 16; ++rr) {
            const float4 a = *(const float4*)&T[rr][sr*4];
            const float4 b = *(const float4*)&T[rr][sc];
            g[0][0]+=a.x*b.x; g[0][1]+=a.x*b.y; g[0][2]+=a.x*b.z; g[0][3]+=a.x*b.w;
            g[1][0]+=a.y*b.x; g[1][1]+=a.y*b.y; g[1][2]+=a.y*b.z; g[1][3]+=a.y*b.w;
            g[2][0]+=a.z*b.x; g[2][1]+=a.z*b.y; g[2][2]+=a.z*b.z; g[2][3]+=a.z*b.w;
            g[3][0]+=a.w*b.x; g[3][1]+=a.w*b.y; g[3][2]+=a.w*b.z; g[3][3]+=a.w*b.w;
        }
        cs += T[qq*4+0][col] + T[qq*4+1][col] + T[qq*4+2][col] + T[qq*4+3][col];
    }
    float* outp = parts + (i64)((blockIdx.z*gridDim.y + blockIdx.y)*gridDim.x + blockIdx.x)*4160;
    #pragma unroll
    for (int xx = 0; xx < 4; ++xx)
        #pragma unroll
        for (int yy = 0; yy < 4; ++yy)
            outp[(sr*4+xx)*64 + sc + yy] = g[xx][yy];
    csred[qq][col] = cs;
    __syncthreads();
    if (tid < 64) outp[4096 + tid] = csred[0][tid]+csred[1][tid]+csred[2][tid]+csred[3][tid];
}

// scale/shift per (s,z): S1 = qbar.kbar, S2 = <G_Q, G_K>_F
__global__ __launch_bounds__(256) void fin_stats(
    const float* __restrict__ gq, const float* __restrict__ gk,
    float* __restrict__ ss)
{
    const int z = blockIdx.x, s = blockIdx.y;
    const int tid = threadIdx.x;
    const int lane = tid & 63, wid = tid >> 6;
    const float* q0 = gq + (i64)((s*2+0)*32 + z)*4160;
    const float* q1 = gq + (i64)((s*2+1)*32 + z)*4160;
    float p2 = 0.f;
    for (int i = tid; i < 4096; i += 256) {
        float a = q0[i] + q1[i];
        float b = 0.f;
        #pragma unroll
        for (int c = 0; c < 8; ++c) b += gk[(i64)(c*32 + z)*4160 + i];
        p2 += a*b;
    }
    float p1 = 0.f;
    if (tid < 64) {
        float a = q0[4096+tid] + q1[4096+tid];
        float b = 0.f;
        #pragma unroll
        for (int c = 0; c < 8; ++c) b += gk[(i64)(c*32 + z)*4160 + 4096 + tid];
        p1 = a*b;
    }
    #pragma unroll
    for (int off = 32; off; off >>= 1) { p2 += __shfl_xor(p2, off); p1 += __shfl_xor(p1, off); }
    __shared__ float r2[4], r1[4];
    if (lane == 0) { r2[wid] = p2; r1[wid] = p1; }
    __syncthreads();
    if (tid == 0) {
        float S2 = r2[0]+r2[1]+r2[2]+r2[3];
        float S1 = r1[0]+r1[1]+r1[2]+r1[3];
        const float inv = 1.f/1048576.f;
        float mu = S1*inv;
        float var = fmaxf(S2*inv - mu*mu, 0.f);
        float sc = rsqrtf(var + 1e-5f);
        ss[(s*32+z)*2] = sc;
        ss[(s*32+z)*2+1] = sc*mu;
    }
}

// ---------------- fused spatial flash attention: swapped QK^T, vectorized P ----
// S^T = mfma(K, Q): D reg-index dim = kv, lane-col = q. P stored [q][64 kv] with
// 3-bit octet swizzle (oct ^ q&7): writes = b64-pairs, PV A-reads conflict-free.
__global__ __launch_bounds__(256) void flash_ps(
    const ushort* __restrict__ Qp, const ushort* __restrict__ Kp,
    const ushort* __restrict__ Vtp, const float* __restrict__ ss,
    ushort* __restrict__ ctxp)
{
    __shared__ ushort Ph[4096], Pl[4096];          // Q in prologue, P [q][kv] in loop
    __shared__ ushort Kh[2][4096], Kl[2][4096];
    __shared__ ushort Vh[2][4096], Vl[2][4096];
    int wg = blockIdx.x;                           // plain linear decode
    const int qt = wg & 7, zz = (wg >> 3) & 31, s = wg >> 8;
    const int b = zz >> 3, hD = (zz & 7) * 64;
    const float scale = ss[(s*32+zz)*2], shift = ss[(s*32+zz)*2+1];
    const ushort* Qb = Qp + (i64)s*2097152 + (i64)b*262144 + (i64)(qt*64)*512 + hD;
    const ushort* Kb = Kp + (i64)b*1048576 + hD;
    const ushort* Vb = Vtp + (i64)b*1048576 + (i64)hD*2048;
    const int tid = threadIdx.x, lane = tid & 63, wid = tid >> 6;
    const int fr = lane & 15, kc = lane >> 4;
    const int wkv = wid >> 1, wq2 = wid & 1;       // QK^T wave roles
    const int wq3 = wid >> 1, wd  = wid & 1;       // PV wave roles

    auto stage64 = [&](const ushort* src, i64 ld, i64 lo, ushort* Lh, ushort* Ll){
        #pragma unroll
        for (int q = 0; q < 2; ++q) {
            int rb = wid*16 + q*8;
            int r = rb + (lane >> 3);
            int gs = (lane & 7) ^ (r & 7);
            const ushort* p = src + (i64)r*ld + gs*8;
            glds16(p,      &Lh[rb*64]);
            glds16(p + lo, &Ll[rb*64]);
        }
    };

    stage64(Qb, 512, 1048576, Ph, Pl);             // Q staged into P buffers
    stage64(Kb, 512, 4194304, Kh[0], Kl[0]);
    stage64(Vb, 2048, 4194304, Vh[0], Vl[0]);
    VMCNT(8); SBAR;                                // Q resident
    bf16x8 qh[2][2], ql[2][2];                     // [j][ks]: B-frags for QK^T
    #pragma unroll
    for (int j = 0; j < 2; ++j)
        #pragma unroll
        for (int ks = 0; ks < 2; ++ks) {
            int row = wq2*32 + j*16 + fr;
            qh[j][ks] = fragS(Ph, row, ks*4 + kc);
            ql[j][ks] = fragS(Pl, row, ks*4 + kc);
        }
    LGKM0; SBAR;                                   // Q hoisted; P buffers free
    SCHED0;
    stage64(Kb + (i64)64*512, 512, 4194304, Kh[1], Kl[1]);
    stage64(Vb + 64, 2048, 4194304, Vh[1], Vl[1]);

    f32x4 ctx[2][2];
    #pragma unroll
    for (int i = 0; i < 2; ++i)
        #pragma unroll
        for (int j = 0; j < 2; ++j) ctx[i][j] = (f32x4){0.f,0.f,0.f,0.f};
    float dl[2] = {0.f, 0.f};

    for (int t = 0; t < 32; ++t) {
        const int cur = t & 1;
        if (t < 31) { VMCNT(8); } else { VMCNT(0); }
        SBAR;
        // ---- S^T = K . Q^T : sacc[i][j] rows = kv, cols = q ----
        f32x4 sacc[2][2];
        #pragma unroll
        for (int i = 0; i < 2; ++i)
            #pragma unroll
            for (int j = 0; j < 2; ++j) sacc[i][j] = (f32x4){0.f,0.f,0.f,0.f};
        #pragma unroll
        for (int ks = 0; ks < 2; ++ks) {
            bf16x8 khf[2], klf[2];
            #pragma unroll
            for (int i = 0; i < 2; ++i) {
                int row = wkv*32 + i*16 + fr;
                khf[i] = fragS(Kh[cur], row, ks*4 + kc);
                klf[i] = fragS(Kl[cur], row, ks*4 + kc);
            }
            __builtin_amdgcn_s_setprio(1);
            #pragma unroll
            for (int i = 0; i < 2; ++i)
                #pragma unroll
                for (int j = 0; j < 2; ++j) {
                    sacc[i][j] = MFMA_BF16(khf[i], qh[j][ks], sacc[i][j], 0, 0, 0);
                    sacc[i][j] = MFMA_BF16(khf[i], ql[j][ks], sacc[i][j], 0, 0, 0);
                    sacc[i][j] = MFMA_BF16(klf[i], qh[j][ks], sacc[i][j], 0, 0, 0);
                }
            __builtin_amdgcn_s_setprio(0);
        }
        // ---- P = exp(scale*s - shift); den; vectorized swizzled store ----
        #pragma unroll
        for (int i = 0; i < 2; ++i)
            #pragma unroll
            for (int j = 0; j < 2; ++j) {
                ushort h4[4], l4[4];
                #pragma unroll
                for (int r = 0; r < 4; ++r) {
                    float p = __expf(sacc[i][j][r]*scale - shift);
                    dl[j] += p;
                    split1(p, h4[r], l4[r]);
                }
                int q = wq2*32 + j*16 + fr;
                int oct = wkv*4 + i*2 + (kc >> 1);
                int ad = q*64 + ((oct ^ (q & 7)) << 3) + ((kc & 1) << 2);
                *(ushort4*)&Ph[ad] = make_ushort4(h4[0],h4[1],h4[2],h4[3]);
                *(ushort4*)&Pl[ad] = make_ushort4(l4[0],l4[1],l4[2],l4[3]);
            }
        LGKM0; SBAR;                           // P visible; K[cur] reads done
        SCHED0;
        if (t < 30) stage64(Kb + (i64)((t+2)*64)*512, 512, 4194304, Kh[cur], Kl[cur]);
        // ---- ctx += P V : A = P[q][kv] (swizzled), B = V^T rows = d ----
        #pragma unroll
        for (int ks = 0; ks < 2; ++ks) {
            bf16x8 vhf[2], vlf[2], pah[2], pal[2];
            #pragma unroll
            for (int j = 0; j < 2; ++j) {
                int row = wd*32 + j*16 + fr;
                vhf[j] = fragS(Vh[cur], row, ks*4 + kc);
                vlf[j] = fragS(Vl[cur], row, ks*4 + kc);
            }
            #pragma unroll
            for (int i = 0; i < 2; ++i) {
                int q = wq3*32 + i*16 + fr;
                int o = ks*4 + kc;
                pah[i] = *(const bf16x8*)&Ph[q*64 + ((o ^ (q & 7)) << 3)];
                pal[i] = *(const bf16x8*)&Pl[q*64 + ((o ^ (q & 7)) << 3)];
            }
            __builtin_amdgcn_s_setprio(1);
            #pragma unroll
            for (int i = 0; i < 2; ++i)
                #pragma unroll
                for (int j = 0; j < 2; ++j) {
                    ctx[i][j] = MFMA_BF16(pah[i], vhf[j], ctx[i][j], 0, 0, 0);
                    ctx[i][j] = MFMA_BF16(pah[i], vlf[j], ctx[i][j], 0, 0, 0);
                    ctx[i][j] = MFMA_BF16(pal[i], vhf[j], ctx[i][j], 0, 0, 0);
                }
            __builtin_amdgcn_s_setprio(0);
        }
        LGKM0; SBAR;                           // V[cur]+P reads done
        SCHED0;
        if (t < 30) stage64(Vb + (t+2)*64, 2048, 4194304, Vh[cur], Vl[cur]);
    }

    // epilogue: den = reduce dl over kc lanes + across wkv waves (overlay on Pl)
    float* denf = (float*)Pl;
    #pragma unroll
    for (int j = 0; j < 2; ++j) {
        float d = dl[j];
        d += __shfl_xor(d, 16); d += __shfl_xor(d, 32);
        if (kc == 0) denf[wkv*64 + wq2*32 + j*16 + fr] = d;
    }
    __syncthreads();
    ushort* Cb = ctxp + (i64)s*2097152 + (i64)b*262144;
    #pragma unroll
    for (int i = 0; i < 2; ++i)
        #pragma unroll
        for (int j = 0; j < 2; ++j)
            #pragma unroll
            for (int r = 0; r < 4; ++r) {
                int row = wq3*32 + i*16 + kc*4 + r;      // q
                int col = wd*32 + j*16 + fr;             // d
                float dv = denf[row] + denf[64 + row];
                ushort h, l; split1(ctx[i][j][r] / dv, h, l);
                i64 off = (i64)(qt*64 + row)*512 + hD + col;
                Cb[off] = h; Cb[off + 1048576] = l;
            }
}

static inline P4 p4x(const void* a, const void* b, const void* c, const void* d){
    P4 x; x.p[0]=a; x.p[1]=b; x.p[2]=c; x.p[3]=d; return x;
}
static inline P4 p4x(const void* a){ return p4x(a,a,a,a); }
static inline I4 i4x(int a, int b, int c, int d){ I4 x; x.v[0]=a; x.v[1]=b; x.v[2]=c; x.v[3]=d; return x; }
#define TRC(ld) ((1<<30)|(ld))   // transposed plane store with leading dim ld

extern "C" void kernel_launch(void* const* d_in, const int* in_sizes, int n_in,
                              void* d_out, int out_size, void* d_ws, size_t ws_size,
                              hipStream_t stream)
{
    (void)in_sizes; (void)n_in; (void)out_size;
    const float* emb[4] = {(const float*)d_in[0], (const float*)d_in[1],
                           (const float*)d_in[2], (const float*)d_in[3]};
    const float* embC = (const float*)d_in[4];
    const float* Wq[4] = {(const float*)d_in[5], (const float*)d_in[6],
                          (const float*)d_in[7], (const float*)d_in[8]};
    const float* Wk  = (const float*)d_in[9];
    const float* Wv  = (const float*)d_in[10];
    const float* WqC = (const float*)d_in[11];
    const float* WkC = (const float*)d_in[12];
    const float* WvC = (const float*)d_in[13];
    const float* Wo[4] = {(const float*)d_in[14], (const float*)d_in[15],
                          (const float*)d_in[16], (const float*)d_in[17]};
    float* out = (float*)d_out;

    char* ws = (char*)d_ws;
    const size_t MB = 1024*1024;
    if (ws_size < 128*MB + 512) return;
    auto U = [&](size_t mb){ return (ushort*)(ws + mb*MB); };
    float* stats = (float*)(ws + 122*MB);
    float* ssbuf = (float*)(ws + 122*MB + 1024);
    float* GKp   = (float*)(ws + 48*MB);
    float* GQp   = (float*)(ws + 53*MB);
    __half* scores = (__half*)(ws + 16*MB);

    hipMemsetAsync(stats, 0, 512, stream);

    // ---- pre-split embC + all weights ----
    {
        PSJobs J;
        const float* srcs[13] = {embC, WqC, WkC, WvC, Wk, Wv,
                                 Wq[0],Wq[1],Wq[2],Wq[3], Wo[0],Wo[1],Wo[2]};
        ushort* dsts[13] = {U(0),U(16),U(32),U(48),U(64),U(65),
                            U(66),U(67),U(68),U(69), U(70),U(71),U(72)};
        int blks[13] = {2048,2048,2048,2048,128,128, 128,128,128,128, 128,128,128};
        int a = 0;
        for (int j = 0; j < 13; ++j) { J.s[j]=srcs[j]; J.d[j]=dsts[j]; J.st[j]=a; a+=blks[j]; }
        J.st[13] = a;
        presplit<<<dim3(a), 256, 0, stream>>>(J);
    }
    // ---- channel projections: round-6 decode (x inner, y=4, z=12) grid 768 ----
    gemm_ps<128,1><<<dim3(768), 256, 0, stream>>>(
        p4x(U(0)), p4x(U(16), U(32), U(48), U(48)), p4x(U(74), U(90), U(106), U(106)),
        i4x(TRC(512), TRC(512), 2048, 2048), nullptr,
        2048, 4, 4, 16,
        1048576, 2048, 4194304,   0, 2048, 4194304,   1048576, 0, 4194304);
    // ---- pre-split emb1..4 + Wo[3] ----
    {
        PSJobs J;
        const float* srcs[13] = {emb[0], emb[1], emb[2], emb[3], Wo[3],
                                 nullptr,nullptr,nullptr,nullptr,nullptr,nullptr,nullptr,nullptr};
        ushort* dsts[13] = {U(0), U(4), U(8), U(12), U(73),
                            nullptr,nullptr,nullptr,nullptr,nullptr,nullptr,nullptr,nullptr};
        int blks[5] = {512,512,512,512,128};
        int a = 0;
        for (int j = 0; j < 5; ++j) { J.s[j]=srcs[j]; J.d[j]=dsts[j]; J.st[j]=a; a+=blks[j]; }
        for (int j = 5; j < 14; ++j) J.st[j] = a;
        presplit<<<dim3(a), 256, 0, stream>>>(J);
    }
    // ---- attn_c: (16,16,4) grid 1024 ----
    gemm_ps<128,2><<<dim3(1024), 256, 0, stream>>>(
        p4x(U(74)), p4x(U(90)), p4x(scores), i4x(0,0,0,0), stats,
        512, 4, 16, 16,
        1048576, 512, 4194304,   1048576, 512, 4194304,   4194304, 2048, 0);
    softmax_rows<<<dim3(4*2048), 256, 0, stream>>>(scores, U(74), stats, 2048, 1.f/4194304.f);
    // ---- ctx_c: TM=64 (4,32,4) grid 512 ----
    gemm_ps<64,3><<<dim3(512), 256, 0, stream>>>(
        p4x(U(16)), p4x(U(106)), p4x(U(48)), i4x(0,0,0,0), nullptr,
        2048, 4, 32, 4,
        4194304, 2048, 30408704,   1048576, 2048, 4194304,   1048576, 0, 4194304);
    // ---- K/V projections: TM=128 (4,16,8) grid 512 ----
    gemm_ps<128,1><<<dim3(512), 256, 0, stream>>>(
        p4x(U(48)), p4x(U(64), U(65), U(65), U(65)), p4x(U(74), U(90), U(90), U(90)),
        i4x(512, TRC(2048), 0, 0), nullptr,
        512, 4, 16, 4,
        1048576, 512, 4194304,   0, 512, 262144,   1048576, 0, 4194304);
    // ---- Q projections: TM=64 (4,8,16) grid 512 ----
    gemm_ps<64,1><<<dim3(512), 256, 0, stream>>>(
        p4x(U(0), U(4), U(8), U(12)), p4x(U(66), U(67), U(68), U(69)),
        p4x(U(106), U(110), U(114), U(118)),
        i4x(512,512,512,512), nullptr,
        512, 4, 8, 4,
        262144, 512, 1048576,   0, 512, 262144,   262144, 0, 1048576);
    // ---- Gram stats + finalize ----
    gram64<<<dim3(32, 8, 1), 256, 0, stream>>>(U(74), 4194304, GKp, 1048576, 0);
    gram64<<<dim3(32, 2, 4), 256, 0, stream>>>(U(106), 1048576, GQp, 262144, 2097152);
    fin_stats<<<dim3(32, 4), 256, 0, stream>>>(GQp, GKp, ssbuf);
    // ---- fused spatial attention (swapped QK^T, plain decode) ----
    flash_ps<<<dim3(1024), 256, 0, stream>>>(U(106), U(74), U(90), ssbuf, U(16));
    // ---- output projections: TM=64 (4,8,16) grid 512 ----
    gemm_ps<64,0><<<dim3(512), 256, 0, stream>>>(
        p4x(U(16), U(20), U(24), U(28)), p4x(U(70), U(71), U(72), U(73)),
        p4x(out, out + 1048576, out + 2097152, out + 3145728),
        i4x(0,0,0,0), nullptr,
        512, 4, 8, 4,
        262144, 512, 1048576,   0, 512, 262144,   262144, 512, 1048576);
}

// Round 14
// 656.918 us; speedup vs baseline: 1.0070x; 1.0070x over previous
//
#include <hip/hip_runtime.h>
#include <hip/hip_bf16.h>
#include <hip/hip_fp16.h>

typedef long long i64;
typedef unsigned int u32;
typedef __attribute__((ext_vector_type(8))) short bf16x8;
typedef __attribute__((ext_vector_type(4))) float f32x4;

#define MFMA_BF16 __builtin_amdgcn_mfma_f32_16x16x32_bf16
#define VMCNT(n)  asm volatile("s_waitcnt vmcnt(" #n ")" ::: "memory")
#define LGKM0     asm volatile("s_waitcnt lgkmcnt(0)" ::: "memory")
#define SBAR      __builtin_amdgcn_s_barrier()
#define SCHED0    __builtin_amdgcn_sched_barrier(0)

__device__ __forceinline__ void glds16(const void* g, void* l){
    __builtin_amdgcn_global_load_lds((const __attribute__((address_space(1))) u32*)g,
                                     (__attribute__((address_space(3))) u32*)l, 16, 0, 0);
}
// fp32 -> bf16 hi (truncate) + bf16 lo (residual). a ~= hi + lo, |err| ~ 2^-16 |a|
__device__ __forceinline__ void split1(float x, ushort& h, ushort& l){
    unsigned b = __float_as_uint(x);
    h = (ushort)(b >> 16);
    float hf = __uint_as_float(b & 0xFFFF0000u);
    float lf = x - hf;
    l = (ushort)(__float_as_uint(lf) >> 16);
}
__device__ __forceinline__ float bfpair(ushort h, ushort l){
    return __uint_as_float((u32)h << 16) + __uint_as_float((u32)l << 16);
}
// swizzled [64][64] bf16 tile read (flash staging): 16B-group g (0..7) XOR row&7
__device__ __forceinline__ bf16x8 fragS(const ushort* P, int row, int g){
    return *(const bf16x8*)&P[row*64 + (((g) ^ (row & 7)) << 3)];
}

struct P4 { const void* p[4]; };
struct I4 { int v[4]; };

// ---------------- pre-split: fp32 -> bf16 hi/lo planes ----------------
struct PSJobs { const float* s[13]; ushort* d[13]; int st[14]; };
__global__ __launch_bounds__(256) void presplit(PSJobs J){
    int bid = blockIdx.x, j = 0;
    while (bid >= J.st[j+1]) ++j;
    i64 base = (i64)(bid - J.st[j])*2048 + threadIdx.x*8;
    i64 loOff = (i64)(J.st[j+1] - J.st[j])*2048;
    const float* sp = J.s[j]; ushort* dp = J.d[j];
    float4 a = *(const float4*)&sp[base];
    float4 b = *(const float4*)&sp[base+4];
    float v[8] = {a.x,a.y,a.z,a.w,b.x,b.y,b.z,b.w};
    ushort h[8], l[8];
    #pragma unroll
    for (int t = 0; t < 8; ++t) split1(v[t], h[t], l[t]);
    *(ushort4*)&dp[base]         = make_ushort4(h[0],h[1],h[2],h[3]);
    *(ushort4*)&dp[base+4]       = make_ushort4(h[4],h[5],h[6],h[7]);
    *(ushort4*)&dp[loOff+base]   = make_ushort4(l[0],l[1],l[2],l[3]);
    *(ushort4*)&dp[loOff+base+4] = make_ushort4(l[4],l[5],l[6],l[7]);
}

// ---------------- 256x256-tile 8-wave 4-phase GEMM (attn_c only) ----------------
template<int OUT>
__global__ __launch_bounds__(512) void gemm_8p(
    P4 Ap, P4 Bp, P4 Cp, I4 cmode, float* __restrict__ stats,
    int K, int zdiv, int ci, int Y, int X,
    i64 ab2, i64 alda, i64 aLo,
    i64 bb2, i64 bldb, i64 bLo,
    i64 cb2, i64 cld, i64 cLo)
{
    __shared__ ushort Ah[2][8192], Al[2][8192], Bh[2][8192], Bl[2][8192]; // [256][32]
    __shared__ float sred[8], qred[8];
    const int q8 = gridDim.x >> 3;                 // grid % 8 == 0
    int wg = (blockIdx.x & 7) * q8 + (blockIdx.x >> 3);
    const int z2i = wg % ci; wg /= ci;
    const int y = wg % Y;    wg /= Y;
    const int x = wg % X;
    const int zo = wg / X;
    const int z = zo*ci + z2i;
    const int z1 = z / zdiv, z2 = z % zdiv;
    const int m0 = y*256, n0 = x*256;

    const int tid = threadIdx.x, lane = tid & 63, wid = tid >> 6;
    const int wm = wid >> 2, wn = wid & 3, fr = lane & 15, kc = lane >> 4;
    const ushort* Aps = (const ushort*)Ap.p[z1] + (i64)z2*ab2 + (i64)m0*alda;
    const ushort* Bps = (const ushort*)Bp.p[z1] + (i64)z2*bb2 + (i64)n0*bldb;

    auto stage4 = [&](int k0, int pb, int half){
        int r  = half*128 + (tid >> 2);
        int rb = half*128 + (wid << 4);
        int gs = (tid & 3) ^ ((r >> 1) & 3);
        const ushort* sa = Aps + (i64)r*alda + k0 + gs*8;
        glds16(sa,       &Ah[pb][rb*32]);
        glds16(sa + aLo, &Al[pb][rb*32]);
        const ushort* sb = Bps + (i64)r*bldb + k0 + gs*8;
        glds16(sb,       &Bh[pb][rb*32]);
        glds16(sb + bLo, &Bl[pb][rb*32]);
    };
    auto rd = [&](const ushort* P, int row, int kcc)->bf16x8 {
        return *(const bf16x8*)&P[row*32 + ((kcc ^ ((row >> 1) & 3)) << 3)];
    };

    f32x4 acc[8][4];
    #pragma unroll
    for (int i = 0; i < 8; ++i)
        #pragma unroll
        for (int j = 0; j < 4; ++j) acc[i][j] = (f32x4){0.f,0.f,0.f,0.f};

    const int NT = K >> 5;
    stage4(0, 0, 0); stage4(0, 0, 1);

    for (int t = 0; t < NT; ++t) {
        const int cur = t & 1;
        VMCNT(0); SBAR;
        bf16x8 b_h[4], b_l[4];
        #pragma unroll
        for (int p = 0; p < 4; ++p) {
            bf16x8 a_h[2], a_l[2];
            if (p == 0) {
                #pragma unroll
                for (int j = 0; j < 4; ++j) {
                    int row = wn*64 + j*16 + fr;
                    b_h[j] = rd(Bh[cur], row, kc);
                    b_l[j] = rd(Bl[cur], row, kc);
                }
            }
            #pragma unroll
            for (int e = 0; e < 2; ++e) {
                int row = wm*128 + (p*2 + e)*16 + fr;
                a_h[e] = rd(Ah[cur], row, kc);
                a_l[e] = rd(Al[cur], row, kc);
            }
            if (p < 2 && t + 1 < NT) stage4((t+1) << 5, cur ^ 1, p);
            SBAR;
            __builtin_amdgcn_s_setprio(1);
            #pragma unroll
            for (int e = 0; e < 2; ++e)
                #pragma unroll
                for (int j = 0; j < 4; ++j) {
                    acc[p*2+e][j] = MFMA_BF16(a_h[e], b_h[j], acc[p*2+e][j], 0, 0, 0);
                    acc[p*2+e][j] = MFMA_BF16(a_h[e], b_l[j], acc[p*2+e][j], 0, 0, 0);
                    acc[p*2+e][j] = MFMA_BF16(a_l[e], b_h[j], acc[p*2+e][j], 0, 0, 0);
                }
            __builtin_amdgcn_s_setprio(0);
            SBAR;
        }
    }

    const i64 cbase = (i64)z2*cb2;
    if (OUT == 1) {
        ushort* C = (ushort*)Cp.p[z1];
        const int cfg = cmode.v[z1];
        const int tr = cfg >> 30;
        const i64 ldv = cfg & 0x3FFFFFFF;
        #pragma unroll
        for (int i = 0; i < 8; ++i)
            #pragma unroll
            for (int j = 0; j < 4; ++j)
                #pragma unroll
                for (int r = 0; r < 4; ++r) {
                    int m = m0 + wm*128 + i*16 + kc*4 + r;
                    int n = n0 + wn*64 + j*16 + fr;
                    ushort h, l; split1(acc[i][j][r], h, l);
                    i64 off = cbase + (tr ? (i64)n*ldv + m : (i64)m*ldv + n);
                    C[off] = h; C[off + cLo] = l;
                }
    } else {
        __half* C = (__half*)Cp.p[z1];
        float ls = 0.f, lq = 0.f;
        #pragma unroll
        for (int i = 0; i < 8; ++i)
            #pragma unroll
            for (int j = 0; j < 4; ++j)
                #pragma unroll
                for (int r = 0; r < 4; ++r) {
                    int m = m0 + wm*128 + i*16 + kc*4 + r;
                    int n = n0 + wn*64 + j*16 + fr;
                    float v = acc[i][j][r];
                    ls += v; lq += v*v;
                    C[cbase + (i64)m*cld + n] = __float2half(v);
                }
        #pragma unroll
        for (int off = 32; off; off >>= 1) { ls += __shfl_xor(ls, off); lq += __shfl_xor(lq, off); }
        if (lane == 0) { sred[wid] = ls; qred[wid] = lq; }
        __syncthreads();
        if (tid == 0) {
            float s = 0.f, qq = 0.f;
            #pragma unroll
            for (int w = 0; w < 8; ++w) { s += sred[w]; qq += qred[w]; }
            atomicAdd(&stats[2*z],   s);
            atomicAdd(&stats[2*z+1], qq);
        }
    }
}

// ---------------- TMx128-tile GEMM on pre-split planes, bf16x3, counted vmcnt ----
// XCD-swizzled 1D decode (round-12 config).
template<int TM, int OUT>
__global__ __launch_bounds__(256) void gemm_ps(
    P4 Ap, P4 Bp, P4 Cp, I4 cmode, float* __restrict__ stats,
    int K, int zdiv, int ci, int Y, int X,
    i64 ab2, i64 alda, i64 aLo,
    i64 bb2, i64 bldb, i64 bLo,
    i64 cb2, i64 cld, i64 cLo)
{
    constexpr int CW = (TM == 128) ? 64 : 32;
    constexpr int FJ = CW / 16;
    __shared__ ushort Ah[2][TM*32], Al[2][TM*32];
    __shared__ ushort Bh[2][4096], Bl[2][4096];
    __shared__ float sred[4], qred[4];
    const int q8 = gridDim.x >> 3;
    int wg = (blockIdx.x & 7) * q8 + (blockIdx.x >> 3);
    const int z2i = wg % ci; wg /= ci;
    const int y = wg % Y;    wg /= Y;
    const int x = wg % X;
    const int zo = wg / X;
    const int z = zo*ci + z2i;
    const int z1 = z / zdiv, z2 = z % zdiv;
    const int m0 = y*TM, n0 = x*128;

    const int tid = threadIdx.x, lane = tid & 63, wid = tid >> 6;
    const int wm = (TM == 128) ? (wid >> 1) : 0;
    const int wn = (TM == 128) ? (wid & 1) : wid;
    const int fr = lane & 15, kc = lane >> 4;
    const ushort* Aps = (const ushort*)Ap.p[z1] + (i64)z2*ab2 + (i64)m0*alda;
    const ushort* Bps = (const ushort*)Bp.p[z1] + (i64)z2*bb2 + (i64)n0*bldb;

    auto stageAB = [&](int k0, int pb){
        if constexpr (TM == 128) {
            #pragma unroll
            for (int q = 0; q < 2; ++q) {
                int r  = wid*32 + (lane >> 2) + q*16;
                int gs = (lane & 3) ^ ((r >> 1) & 3);
                const ushort* sa = Aps + (i64)r*alda + k0 + gs*8;
                glds16(sa,       &Ah[pb][(wid*32+q*16)*32]);
                glds16(sa + aLo, &Al[pb][(wid*32+q*16)*32]);
            }
        } else {
            int r  = wid*16 + (lane >> 2);
            int gs = (lane & 3) ^ ((r >> 1) & 3);
            const ushort* sa = Aps + (i64)r*alda + k0 + gs*8;
            glds16(sa,       &Ah[pb][(wid*16)*32]);
            glds16(sa + aLo, &Al[pb][(wid*16)*32]);
        }
        #pragma unroll
        for (int q = 0; q < 2; ++q) {
            int r  = wid*32 + (lane >> 2) + q*16;
            int gs = (lane & 3) ^ ((r >> 1) & 3);
            const ushort* sb = Bps + (i64)r*bldb + k0 + gs*8;
            glds16(sb,       &Bh[pb][(wid*32+q*16)*32]);
            glds16(sb + bLo, &Bl[pb][(wid*32+q*16)*32]);
        }
    };
    auto rd = [&](const ushort* P, int row, int kcc)->bf16x8 {
        return *(const bf16x8*)&P[row*32 + ((kcc ^ ((row >> 1) & 3)) << 3)];
    };

    f32x4 acc[4][FJ];
    #pragma unroll
    for (int i = 0; i < 4; ++i)
        #pragma unroll
        for (int j = 0; j < FJ; ++j) acc[i][j] = (f32x4){0.f,0.f,0.f,0.f};

    const int NT = K >> 5;
    stageAB(0, 0); stageAB(32, 1);

    for (int t = 0; t < NT; ++t) {
        const int cur = t & 1;
        if (t + 1 < NT) {
            if constexpr (TM == 128) { VMCNT(8); } else { VMCNT(6); }
        } else { VMCNT(0); }
        SBAR;
        bf16x8 a_h[4], a_l[4], b_h[FJ], b_l[FJ];
        #pragma unroll
        for (int i = 0; i < 4; ++i) {
            int row = wm*64 + i*16 + fr;
            a_h[i] = rd(Ah[cur], row, kc);
            a_l[i] = rd(Al[cur], row, kc);
        }
        #pragma unroll
        for (int j = 0; j < FJ; ++j) {
            int row = wn*CW + j*16 + fr;
            b_h[j] = rd(Bh[cur], row, kc);
            b_l[j] = rd(Bl[cur], row, kc);
        }
        __builtin_amdgcn_s_setprio(1);
        #pragma unroll
        for (int i = 0; i < 4; ++i)
            #pragma unroll
            for (int j = 0; j < FJ; ++j) {
                acc[i][j] = MFMA_BF16(a_h[i], b_h[j], acc[i][j], 0, 0, 0);
                acc[i][j] = MFMA_BF16(a_h[i], b_l[j], acc[i][j], 0, 0, 0);
                acc[i][j] = MFMA_BF16(a_l[i], b_h[j], acc[i][j], 0, 0, 0);
            }
        __builtin_amdgcn_s_setprio(0);
        LGKM0;
        SBAR;
        SCHED0;
        if (t + 2 < NT) stageAB((t+2) << 5, cur);
    }

    const i64 cbase = (i64)z2*cb2;
    if (OUT == 0) {
        float* C = (float*)Cp.p[z1];
        #pragma unroll
        for (int i = 0; i < 4; ++i)
            #pragma unroll
            for (int j = 0; j < FJ; ++j)
                #pragma unroll
                for (int r = 0; r < 4; ++r) {
                    int m = m0 + wm*64 + i*16 + kc*4 + r;
                    int n = n0 + wn*CW + j*16 + fr;
                    C[cbase + (i64)m*cld + n] = acc[i][j][r];
                }
    } else if (OUT == 1) {
        ushort* C = (ushort*)Cp.p[z1];
        const int cfg = cmode.v[z1];
        const int tr = cfg >> 30;
        const i64 ldv = cfg & 0x3FFFFFFF;
        #pragma unroll
        for (int i = 0; i < 4; ++i)
            #pragma unroll
            for (int j = 0; j < FJ; ++j)
                #pragma unroll
                for (int r = 0; r < 4; ++r) {
                    int m = m0 + wm*64 + i*16 + kc*4 + r;
                    int n = n0 + wn*CW + j*16 + fr;
                    ushort h, l; split1(acc[i][j][r], h, l);
                    i64 off = cbase + (tr ? (i64)n*ldv + m : (i64)m*ldv + n);
                    C[off] = h; C[off + cLo] = l;
                }
    } else if (OUT == 2) {
        __half* C = (__half*)Cp.p[z1];
        float ls = 0.f, lq = 0.f;
        #pragma unroll
        for (int i = 0; i < 4; ++i)
            #pragma unroll
            for (int j = 0; j < FJ; ++j)
                #pragma unroll
                for (int r = 0; r < 4; ++r) {
                    int m = m0 + wm*64 + i*16 + kc*4 + r;
                    int n = n0 + wn*CW + j*16 + fr;
                    float v = acc[i][j][r];
                    ls += v; lq += v*v;
                    C[cbase + (i64)m*cld + n] = __float2half(v);
                }
        #pragma unroll
        for (int off = 32; off; off >>= 1) { ls += __shfl_xor(ls, off); lq += __shfl_xor(lq, off); }
        if (lane == 0) { sred[wid] = ls; qred[wid] = lq; }
        __syncthreads();
        if (tid == 0) {
            atomicAdd(&stats[2*z],   sred[0]+sred[1]+sred[2]+sred[3]);
            atomicAdd(&stats[2*z+1], qred[0]+qred[1]+qred[2]+qred[3]);
        }
    } else {
        ushort* C = (ushort*)Cp.p[z1];
        #pragma unroll
        for (int i = 0; i < 4; ++i)
            #pragma unroll
            for (int j = 0; j < FJ; ++j)
                #pragma unroll
                for (int r = 0; r < 4; ++r) {
                    int m = m0 + wm*64 + i*16 + kc*4 + r;
                    int n = n0 + wn*CW + j*16 + fr;
                    ushort h, l; split1(acc[i][j][r], h, l);
                    i64 off = cbase + ((i64)(m >> 9) << 18) + ((i64)n << 9) + (m & 511);
                    C[off] = h; C[off + cLo] = l;
                }
    }
}

// ---------------- channel softmax: fp16 scores in -> sim bf16 hi/lo planes out ----
__global__ __launch_bounds__(256) void softmax_rows(
    __half* __restrict__ attn, ushort* __restrict__ lo,
    const float* __restrict__ stats, int rows_per_stat, float inv_count)
{
    const int ROWLEN = 2048;
    const int row = blockIdx.x;
    const int sidx = row / rows_per_stat;
    float sm = stats[2*sidx], sq = stats[2*sidx+1];
    float mean = sm * inv_count;
    float var = fmaxf(sq * inv_count - mean*mean, 0.f);
    float scale = rsqrtf(var + 1e-5f);
    __half* rp = attn + (i64)row * ROWLEN;
    ushort* hp = (ushort*)rp;
    ushort* lp = lo + (i64)row * ROWLEN;
    const int tid = threadIdx.x;
    float v[8]; float mx = -3.4e38f;
    #pragma unroll
    for (int s = 0; s < 8; ++s) { float x = __half2float(rp[tid + s*256]) * scale; v[s] = x; mx = fmaxf(mx, x); }
    #pragma unroll
    for (int off = 32; off; off >>= 1) mx = fmaxf(mx, __shfl_xor(mx, off));
    __shared__ float red[4];
    if ((tid & 63) == 0) red[tid >> 6] = mx;
    __syncthreads();
    mx = fmaxf(fmaxf(red[0], red[1]), fmaxf(red[2], red[3]));
    float ls = 0.f;
    #pragma unroll
    for (int s = 0; s < 8; ++s) { float e = __expf(v[s] - mx); v[s] = e; ls += e; }
    #pragma unroll
    for (int off = 32; off; off >>= 1) ls += __shfl_xor(ls, off);
    __syncthreads();
    if ((tid & 63) == 0) red[tid >> 6] = ls;
    __syncthreads();
    float inv = 1.f / (red[0] + red[1] + red[2] + red[3]);
    #pragma unroll
    for (int s = 0; s < 8; ++s) {
        ushort h, l; split1(v[s] * inv, h, l);
        hp[tid + s*256] = h; lp[tid + s*256] = l;
    }
}

// ---------------- 64x64 Gram partials + column sums over 256 rows (planes input) ----------------
__global__ __launch_bounds__(256) void gram64(
    const ushort* __restrict__ hi, i64 loOff, float* __restrict__ parts,
    i64 bstride, i64 zs2)
{
    __shared__ float T[16][68];
    __shared__ float csred[4][64];
    const int z = blockIdx.x;
    const int tid = threadIdx.x;
    const ushort* base = hi + (i64)(z>>3)*bstride + (i64)blockIdx.z*zs2
                       + (i64)blockIdx.y*256*512 + (z&7)*64;
    float g[4][4] = {{0.f}};
    float cs = 0.f;
    const int sr = tid >> 4, sc = (tid & 15) * 4;
    const int col = tid & 63, qq = tid >> 6;
    for (int grp = 0; grp < 16; ++grp) {
        i64 idx = (i64)(grp*16 + sr)*512 + sc;
        ushort4 hv = *(const ushort4*)&base[idx];
        ushort4 lv = *(const ushort4*)&base[loOff + idx];
        float4 ld;
        ld.x = bfpair(hv.x, lv.x); ld.y = bfpair(hv.y, lv.y);
        ld.z = bfpair(hv.z, lv.z); ld.w = bfpair(hv.w, lv.w);
        __syncthreads();
        *(float4*)&T[sr][sc] = ld;
        __syncthreads();
        #pragma unroll
        for (int rr = 0; rr < 16; ++rr) {
            const float4 a = *(const float4*)&T[rr][sr*4];
            const float4 b = *(const float4*)&T[rr][sc];
            g[0][0]+=a.x*b.x; g[0][1]+=a.x*b.y; g[0][2]+=a.x*b.z; g[0][3]+=a.x*b.w;
            g[1][0]+=a.y*b.x; g[1][1]+=a.y*b.y; g[1][2]+=a.y*b.z; g[1][3]+=a.y*b.w;
            g[2][0]+=a.z*b.x; g[2][1]+=a.z*b.y; g[2][2]+=a.z*b.z; g[2][3]+=a.z*b.w;
            g[3][0]+=a.w*b.x; g[3][1]+=a.w*b.y; g[3][2]+=a.w*b.z; g[3][3]+=a.w*b.w;
        }
        cs += T[qq*4+0][col] + T[qq*4+1][col] + T[qq*4+2][col] + T[qq*4+3][col];
    }
    float* outp = parts + (i64)((blockIdx.z*gridDim.y + blockIdx.y)*gridDim.x + blockIdx.x)*4160;
    #pragma unroll
    for (int xx = 0; xx < 4; ++xx)
        #pragma unroll
        for (int yy = 0; yy < 4; ++yy)
            outp[(sr*4+xx)*64 + sc + yy] = g[xx][yy];
    csred[qq][col] = cs;
    __syncthreads();
    if (tid < 64) outp[4096 + tid] = csred[0][tid]+csred[1][tid]+csred[2][tid]+csred[3][tid];
}

// scale/shift per (s,z): S1 = qbar.kbar, S2 = <G_Q, G_K>_F
__global__ __launch_bounds__(256) void fin_stats(
    const float* __restrict__ gq, const float* __restrict__ gk,
    float* __restrict__ ss)
{
    const int z = blockIdx.x, s = blockIdx.y;
    const int tid = threadIdx.x;
    const int lane = tid & 63, wid = tid >> 6;
    const float* q0 = gq + (i64)((s*2+0)*32 + z)*4160;
    const float* q1 = gq + (i64)((s*2+1)*32 + z)*4160;
    float p2 = 0.f;
    for (int i = tid; i < 4096; i += 256) {
        float a = q0[i] + q1[i];
        float b = 0.f;
        #pragma unroll
        for (int c = 0; c < 8; ++c) b += gk[(i64)(c*32 + z)*4160 + i];
        p2 += a*b;
    }
    float p1 = 0.f;
    if (tid < 64) {
        float a = q0[4096+tid] + q1[4096+tid];
        float b = 0.f;
        #pragma unroll
        for (int c = 0; c < 8; ++c) b += gk[(i64)(c*32 + z)*4160 + 4096 + tid];
        p1 = a*b;
    }
    #pragma unroll
    for (int off = 32; off; off >>= 1) { p2 += __shfl_xor(p2, off); p1 += __shfl_xor(p1, off); }
    __shared__ float r2[4], r1[4];
    if (lane == 0) { r2[wid] = p2; r1[wid] = p1; }
    __syncthreads();
    if (tid == 0) {
        float S2 = r2[0]+r2[1]+r2[2]+r2[3];
        float S1 = r1[0]+r1[1]+r1[2]+r1[3];
        const float inv = 1.f/1048576.f;
        float mu = S1*inv;
        float var = fmaxf(S2*inv - mu*mu, 0.f);
        float sc = rsqrtf(var + 1e-5f);
        ss[(s*32+z)*2] = sc;
        ss[(s*32+z)*2+1] = sc*mu;
    }
}

// ---------------- fused spatial flash attention: swapped QK^T, vectorized P ----
// XCD-swizzled 1D decode (qt-blocks of one (zz,s) co-located on an XCD).
__global__ __launch_bounds__(256) void flash_ps(
    const ushort* __restrict__ Qp, const ushort* __restrict__ Kp,
    const ushort* __restrict__ Vtp, const float* __restrict__ ss,
    ushort* __restrict__ ctxp)
{
    __shared__ ushort Ph[4096], Pl[4096];          // Q in prologue, P [q][kv] in loop
    __shared__ ushort Kh[2][4096], Kl[2][4096];
    __shared__ ushort Vh[2][4096], Vl[2][4096];
    const int q8g = gridDim.x >> 3;
    int wg = (blockIdx.x & 7) * q8g + (blockIdx.x >> 3);
    const int qt = wg & 7, zz = (wg >> 3) & 31, s = wg >> 8;
    const int b = zz >> 3, hD = (zz & 7) * 64;
    const float scale = ss[(s*32+zz)*2], shift = ss[(s*32+zz)*2+1];
    const ushort* Qb = Qp + (i64)s*2097152 + (i64)b*262144 + (i64)(qt*64)*512 + hD;
    const ushort* Kb = Kp + (i64)b*1048576 + hD;
    const ushort* Vb = Vtp + (i64)b*1048576 + (i64)hD*2048;
    const int tid = threadIdx.x, lane = tid & 63, wid = tid >> 6;
    const int fr = lane & 15, kc = lane >> 4;
    const int wkv = wid >> 1, wq2 = wid & 1;       // QK^T wave roles
    const int wq3 = wid >> 1, wd  = wid & 1;       // PV wave roles

    auto stage64 = [&](const ushort* src, i64 ld, i64 lo, ushort* Lh, ushort* Ll){
        #pragma unroll
        for (int q = 0; q < 2; ++q) {
            int rb = wid*16 + q*8;
            int r = rb + (lane >> 3);
            int gs = (lane & 7) ^ (r & 7);
            const ushort* p = src + (i64)r*ld + gs*8;
            glds16(p,      &Lh[rb*64]);
            glds16(p + lo, &Ll[rb*64]);
        }
    };

    stage64(Qb, 512, 1048576, Ph, Pl);
    stage64(Kb, 512, 4194304, Kh[0], Kl[0]);
    stage64(Vb, 2048, 4194304, Vh[0], Vl[0]);
    VMCNT(8); SBAR;
    bf16x8 qh[2][2], ql[2][2];
    #pragma unroll
    for (int j = 0; j < 2; ++j)
        #pragma unroll
        for (int ks = 0; ks < 2; ++ks) {
            int row = wq2*32 + j*16 + fr;
            qh[j][ks] = fragS(Ph, row, ks*4 + kc);
            ql[j][ks] = fragS(Pl, row, ks*4 + kc);
        }
    LGKM0; SBAR;
    SCHED0;
    stage64(Kb + (i64)64*512, 512, 4194304, Kh[1], Kl[1]);
    stage64(Vb + 64, 2048, 4194304, Vh[1], Vl[1]);

    f32x4 ctx[2][2];
    #pragma unroll
    for (int i = 0; i < 2; ++i)
        #pragma unroll
        for (int j = 0; j < 2; ++j) ctx[i][j] = (f32x4){0.f,0.f,0.f,0.f};
    float dl[2] = {0.f, 0.f};

    for (int t = 0; t < 32; ++t) {
        const int cur = t & 1;
        if (t < 31) { VMCNT(8); } else { VMCNT(0); }
        SBAR;
        f32x4 sacc[2][2];
        #pragma unroll
        for (int i = 0; i < 2; ++i)
            #pragma unroll
            for (int j = 0; j < 2; ++j) sacc[i][j] = (f32x4){0.f,0.f,0.f,0.f};
        #pragma unroll
        for (int ks = 0; ks < 2; ++ks) {
            bf16x8 khf[2], klf[2];
            #pragma unroll
            for (int i = 0; i < 2; ++i) {
                int row = wkv*32 + i*16 + fr;
                khf[i] = fragS(Kh[cur], row, ks*4 + kc);
                klf[i] = fragS(Kl[cur], row, ks*4 + kc);
            }
            __builtin_amdgcn_s_setprio(1);
            #pragma unroll
            for (int i = 0; i < 2; ++i)
                #pragma unroll
                for (int j = 0; j < 2; ++j) {
                    sacc[i][j] = MFMA_BF16(khf[i], qh[j][ks], sacc[i][j], 0, 0, 0);
                    sacc[i][j] = MFMA_BF16(khf[i], ql[j][ks], sacc[i][j], 0, 0, 0);
                    sacc[i][j] = MFMA_BF16(klf[i], qh[j][ks], sacc[i][j], 0, 0, 0);
                }
            __builtin_amdgcn_s_setprio(0);
        }
        #pragma unroll
        for (int i = 0; i < 2; ++i)
            #pragma unroll
            for (int j = 0; j < 2; ++j) {
                ushort h4[4], l4[4];
                #pragma unroll
                for (int r = 0; r < 4; ++r) {
                    float p = __expf(sacc[i][j][r]*scale - shift);
                    dl[j] += p;
                    split1(p, h4[r], l4[r]);
                }
                int q = wq2*32 + j*16 + fr;
                int oct = wkv*4 + i*2 + (kc >> 1);
                int ad = q*64 + ((oct ^ (q & 7)) << 3) + ((kc & 1) << 2);
                *(ushort4*)&Ph[ad] = make_ushort4(h4[0],h4[1],h4[2],h4[3]);
                *(ushort4*)&Pl[ad] = make_ushort4(l4[0],l4[1],l4[2],l4[3]);
            }
        LGKM0; SBAR;
        SCHED0;
        if (t < 30) stage64(Kb + (i64)((t+2)*64)*512, 512, 4194304, Kh[cur], Kl[cur]);
        #pragma unroll
        for (int ks = 0; ks < 2; ++ks) {
            bf16x8 vhf[2], vlf[2], pah[2], pal[2];
            #pragma unroll
            for (int j = 0; j < 2; ++j) {
                int row = wd*32 + j*16 + fr;
                vhf[j] = fragS(Vh[cur], row, ks*4 + kc);
                vlf[j] = fragS(Vl[cur], row, ks*4 + kc);
            }
            #pragma unroll
            for (int i = 0; i < 2; ++i) {
                int q = wq3*32 + i*16 + fr;
                int o = ks*4 + kc;
                pah[i] = *(const bf16x8*)&Ph[q*64 + ((o ^ (q & 7)) << 3)];
                pal[i] = *(const bf16x8*)&Pl[q*64 + ((o ^ (q & 7)) << 3)];
            }
            __builtin_amdgcn_s_setprio(1);
            #pragma unroll
            for (int i = 0; i < 2; ++i)
                #pragma unroll
                for (int j = 0; j < 2; ++j) {
                    ctx[i][j] = MFMA_BF16(pah[i], vhf[j], ctx[i][j], 0, 0, 0);
                    ctx[i][j] = MFMA_BF16(pah[i], vlf[j], ctx[i][j], 0, 0, 0);
                    ctx[i][j] = MFMA_BF16(pal[i], vhf[j], ctx[i][j], 0, 0, 0);
                }
            __builtin_amdgcn_s_setprio(0);
        }
        LGKM0; SBAR;
        SCHED0;
        if (t < 30) stage64(Vb + (t+2)*64, 2048, 4194304, Vh[cur], Vl[cur]);
    }

    float* denf = (float*)Pl;
    #pragma unroll
    for (int j = 0; j < 2; ++j) {
        float d = dl[j];
        d += __shfl_xor(d, 16); d += __shfl_xor(d, 32);
        if (kc == 0) denf[wkv*64 + wq2*32 + j*16 + fr] = d;
    }
    __syncthreads();
    ushort* Cb = ctxp + (i64)s*2097152 + (i64)b*262144;
    #pragma unroll
    for (int i = 0; i < 2; ++i)
        #pragma unroll
        for (int j = 0; j < 2; ++j)
            #pragma unroll
            for (int r = 0; r < 4; ++r) {
                int row = wq3*32 + i*16 + kc*4 + r;
                int col = wd*32 + j*16 + fr;
                float dv = denf[row] + denf[64 + row];
                ushort h, l; split1(ctx[i][j][r] / dv, h, l);
                i64 off = (i64)(qt*64 + row)*512 + hD + col;
                Cb[off] = h; Cb[off + 1048576] = l;
            }
}

static inline P4 p4x(const void* a, const void* b, const void* c, const void* d){
    P4 x; x.p[0]=a; x.p[1]=b; x.p[2]=c; x.p[3]=d; return x;
}
static inline P4 p4x(const void* a){ return p4x(a,a,a,a); }
static inline I4 i4x(int a, int b, int c, int d){ I4 x; x.v[0]=a; x.v[1]=b; x.v[2]=c; x.v[3]=d; return x; }
#define TRC(ld) ((1<<30)|(ld))   // transposed plane store with leading dim ld

extern "C" void kernel_launch(void* const* d_in, const int* in_sizes, int n_in,
                              void* d_out, int out_size, void* d_ws, size_t ws_size,
                              hipStream_t stream)
{
    (void)in_sizes; (void)n_in; (void)out_size;
    const float* emb[4] = {(const float*)d_in[0], (const float*)d_in[1],
                           (const float*)d_in[2], (const float*)d_in[3]};
    const float* embC = (const float*)d_in[4];
    const float* Wq[4] = {(const float*)d_in[5], (const float*)d_in[6],
                          (const float*)d_in[7], (const float*)d_in[8]};
    const float* Wk  = (const float*)d_in[9];
    const float* Wv  = (const float*)d_in[10];
    const float* WqC = (const float*)d_in[11];
    const float* WkC = (const float*)d_in[12];
    const float* WvC = (const float*)d_in[13];
    const float* Wo[4] = {(const float*)d_in[14], (const float*)d_in[15],
                          (const float*)d_in[16], (const float*)d_in[17]};
    float* out = (float*)d_out;

    char* ws = (char*)d_ws;
    const size_t MB = 1024*1024;
    if (ws_size < 128*MB + 512) return;
    auto U = [&](size_t mb){ return (ushort*)(ws + mb*MB); };
    float* stats = (float*)(ws + 122*MB);
    float* ssbuf = (float*)(ws + 122*MB + 1024);
    float* GKp   = (float*)(ws + 48*MB);
    float* GQp   = (float*)(ws + 53*MB);
    __half* scores = (__half*)(ws + 16*MB);

    hipMemsetAsync(stats, 0, 512, stream);

    // ---- pre-split embC + all weights ----
    {
        PSJobs J;
        const float* srcs[13] = {embC, WqC, WkC, WvC, Wk, Wv,
                                 Wq[0],Wq[1],Wq[2],Wq[3], Wo[0],Wo[1],Wo[2]};
        ushort* dsts[13] = {U(0),U(16),U(32),U(48),U(64),U(65),
                            U(66),U(67),U(68),U(69), U(70),U(71),U(72)};
        int blks[13] = {2048,2048,2048,2048,128,128, 128,128,128,128, 128,128,128};
        int a = 0;
        for (int j = 0; j < 13; ++j) { J.s[j]=srcs[j]; J.d[j]=dsts[j]; J.st[j]=a; a+=blks[j]; }
        J.st[13] = a;
        presplit<<<dim3(a), 256, 0, stream>>>(J);
    }
    // ---- channel projections: 128^2 gemm_ps (best measured variant), grid 768 ----
    gemm_ps<128,1><<<dim3(768), 256, 0, stream>>>(
        p4x(U(0)), p4x(U(16), U(32), U(48), U(48)), p4x(U(74), U(90), U(106), U(106)),
        i4x(TRC(512), TRC(512), 2048, 2048), nullptr,
        2048, 4, 4, 4, 16,
        1048576, 2048, 4194304,   0, 2048, 4194304,   1048576, 0, 4194304);
    // ---- pre-split emb1..4 + Wo[3] ----
    {
        PSJobs J;
        const float* srcs[13] = {emb[0], emb[1], emb[2], emb[3], Wo[3],
                                 nullptr,nullptr,nullptr,nullptr,nullptr,nullptr,nullptr,nullptr};
        ushort* dsts[13] = {U(0), U(4), U(8), U(12), U(73),
                            nullptr,nullptr,nullptr,nullptr,nullptr,nullptr,nullptr,nullptr};
        int blks[5] = {512,512,512,512,128};
        int a = 0;
        for (int j = 0; j < 5; ++j) { J.s[j]=srcs[j]; J.d[j]=dsts[j]; J.st[j]=a; a+=blks[j]; }
        for (int j = 5; j < 14; ++j) J.st[j] = a;
        presplit<<<dim3(a), 256, 0, stream>>>(J);
    }
    // ---- attn_c: 8-phase 256^2; grid 256 exact (round-12 config) ----
    gemm_8p<2><<<dim3(256), 512, 0, stream>>>(
        p4x(U(74)), p4x(U(90)), p4x(scores), i4x(0,0,0,0), stats,
        512, 4, 1, 8, 8,
        1048576, 512, 4194304,   1048576, 512, 4194304,   4194304, 2048, 0);
    softmax_rows<<<dim3(4*2048), 256, 0, stream>>>(scores, U(74), stats, 2048, 1.f/4194304.f);
    // ---- ctx_c: TM=64 grid 512 ----
    gemm_ps<64,3><<<dim3(512), 256, 0, stream>>>(
        p4x(U(16)), p4x(U(106)), p4x(U(48)), i4x(0,0,0,0), nullptr,
        2048, 4, 1, 32, 4,
        4194304, 2048, 30408704,   1048576, 2048, 4194304,   1048576, 0, 4194304);
    // ---- K/V projections: TM=128 grid 512 ----
    gemm_ps<128,1><<<dim3(512), 256, 0, stream>>>(
        p4x(U(48)), p4x(U(64), U(65), U(65), U(65)), p4x(U(74), U(90), U(90), U(90)),
        i4x(512, TRC(2048), 0, 0), nullptr,
        512, 4, 4, 16, 4,
        1048576, 512, 4194304,   0, 512, 262144,   1048576, 0, 4194304);
    // ---- Q projections: TM=64 grid 512 ----
    gemm_ps<64,1><<<dim3(512), 256, 0, stream>>>(
        p4x(U(0), U(4), U(8), U(12)), p4x(U(66), U(67), U(68), U(69)),
        p4x(U(106), U(110), U(114), U(118)),
        i4x(512,512,512,512), nullptr,
        512, 4, 4, 8, 4,
        262144, 512, 1048576,   0, 512, 262144,   262144, 0, 1048576);
    // ---- Gram stats + finalize ----
    gram64<<<dim3(32, 8, 1), 256, 0, stream>>>(U(74), 4194304, GKp, 1048576, 0);
    gram64<<<dim3(32, 2, 4), 256, 0, stream>>>(U(106), 1048576, GQp, 262144, 2097152);
    fin_stats<<<dim3(32, 4), 256, 0, stream>>>(GQp, GKp, ssbuf);
    // ---- fused spatial attention (swapped QK^T, XCD-swizzled) ----
    flash_ps<<<dim3(1024), 256, 0, stream>>>(U(106), U(74), U(90), ssbuf, U(16));
    // ---- output projections: TM=64 grid 512 ----
    gemm_ps<64,0><<<dim3(512), 256, 0, stream>>>(
        p4x(U(16), U(20), U(24), U(28)), p4x(U(70), U(71), U(72), U(73)),
        p4x(out, out + 1048576, out + 2097152, out + 3145728),
        i4x(0,0,0,0), nullptr,
        512, 4, 4, 8, 4,
        262144, 512, 1048576,   0, 512, 262144,   262144, 512, 1048576);
}

// Round 15
// 646.694 us; speedup vs baseline: 1.0229x; 1.0158x over previous
//
#include <hip/hip_runtime.h>
#include <hip/hip_bf16.h>
#include <hip/hip_fp16.h>

typedef long long i64;
typedef unsigned int u32;
typedef __attribute__((ext_vector_type(8))) short bf16x8;
typedef __attribute__((ext_vector_type(4))) float f32x4;

#define MFMA_BF16 __builtin_amdgcn_mfma_f32_16x16x32_bf16
#define VMCNT(n)  asm volatile("s_waitcnt vmcnt(" #n ")" ::: "memory")
#define LGKM0     asm volatile("s_waitcnt lgkmcnt(0)" ::: "memory")
#define SBAR      __builtin_amdgcn_s_barrier()
#define SCHED0    __builtin_amdgcn_sched_barrier(0)

__device__ __forceinline__ void glds16(const void* g, void* l){
    __builtin_amdgcn_global_load_lds((const __attribute__((address_space(1))) u32*)g,
                                     (__attribute__((address_space(3))) u32*)l, 16, 0, 0);
}
// fp32 -> bf16 hi (truncate) + bf16 lo (residual). a ~= hi + lo, |err| ~ 2^-16 |a|
__device__ __forceinline__ void split1(float x, ushort& h, ushort& l){
    unsigned b = __float_as_uint(x);
    h = (ushort)(b >> 16);
    float hf = __uint_as_float(b & 0xFFFF0000u);
    float lf = x - hf;
    l = (ushort)(__float_as_uint(lf) >> 16);
}
__device__ __forceinline__ float bfpair(ushort h, ushort l){
    return __uint_as_float((u32)h << 16) + __uint_as_float((u32)l << 16);
}
// swizzled [64][64] bf16 tile read (flash staging): 16B-group g (0..7) XOR row&7
__device__ __forceinline__ bf16x8 fragS(const ushort* P, int row, int g){
    return *(const bf16x8*)&P[row*64 + (((g) ^ (row & 7)) << 3)];
}

struct P4 { const void* p[4]; };
struct I4 { int v[4]; };

// ---------------- pre-split: fp32 -> bf16 hi/lo planes ----------------
struct PSJobs { const float* s[13]; ushort* d[13]; int st[14]; };
__global__ __launch_bounds__(256) void presplit(PSJobs J){
    int bid = blockIdx.x, j = 0;
    while (bid >= J.st[j+1]) ++j;
    i64 base = (i64)(bid - J.st[j])*2048 + threadIdx.x*8;
    i64 loOff = (i64)(J.st[j+1] - J.st[j])*2048;
    const float* sp = J.s[j]; ushort* dp = J.d[j];
    float4 a = *(const float4*)&sp[base];
    float4 b = *(const float4*)&sp[base+4];
    float v[8] = {a.x,a.y,a.z,a.w,b.x,b.y,b.z,b.w};
    ushort h[8], l[8];
    #pragma unroll
    for (int t = 0; t < 8; ++t) split1(v[t], h[t], l[t]);
    *(ushort4*)&dp[base]         = make_ushort4(h[0],h[1],h[2],h[3]);
    *(ushort4*)&dp[base+4]       = make_ushort4(h[4],h[5],h[6],h[7]);
    *(ushort4*)&dp[loOff+base]   = make_ushort4(l[0],l[1],l[2],l[3]);
    *(ushort4*)&dp[loOff+base+4] = make_ushort4(l[4],l[5],l[6],l[7]);
}

// ---------------- 256x256-tile 8-wave 4-phase GEMM (attn_c only) ----------------
template<int OUT>
__global__ __launch_bounds__(512) void gemm_8p(
    P4 Ap, P4 Bp, P4 Cp, I4 cmode, float* __restrict__ stats,
    int K, int zdiv, int ci, int Y, int X,
    i64 ab2, i64 alda, i64 aLo,
    i64 bb2, i64 bldb, i64 bLo,
    i64 cb2, i64 cld, i64 cLo)
{
    __shared__ ushort Ah[2][8192], Al[2][8192], Bh[2][8192], Bl[2][8192]; // [256][32]
    __shared__ float sred[8], qred[8];
    const int q8 = gridDim.x >> 3;                 // grid % 8 == 0
    int wg = (blockIdx.x & 7) * q8 + (blockIdx.x >> 3);
    const int z2i = wg % ci; wg /= ci;
    const int y = wg % Y;    wg /= Y;
    const int x = wg % X;
    const int zo = wg / X;
    const int z = zo*ci + z2i;
    const int z1 = z / zdiv, z2 = z % zdiv;
    const int m0 = y*256, n0 = x*256;

    const int tid = threadIdx.x, lane = tid & 63, wid = tid >> 6;
    const int wm = wid >> 2, wn = wid & 3, fr = lane & 15, kc = lane >> 4;
    const ushort* Aps = (const ushort*)Ap.p[z1] + (i64)z2*ab2 + (i64)m0*alda;
    const ushort* Bps = (const ushort*)Bp.p[z1] + (i64)z2*bb2 + (i64)n0*bldb;

    auto stage4 = [&](int k0, int pb, int half){
        int r  = half*128 + (tid >> 2);
        int rb = half*128 + (wid << 4);
        int gs = (tid & 3) ^ ((r >> 1) & 3);
        const ushort* sa = Aps + (i64)r*alda + k0 + gs*8;
        glds16(sa,       &Ah[pb][rb*32]);
        glds16(sa + aLo, &Al[pb][rb*32]);
        const ushort* sb = Bps + (i64)r*bldb + k0 + gs*8;
        glds16(sb,       &Bh[pb][rb*32]);
        glds16(sb + bLo, &Bl[pb][rb*32]);
    };
    auto rd = [&](const ushort* P, int row, int kcc)->bf16x8 {
        return *(const bf16x8*)&P[row*32 + ((kcc ^ ((row >> 1) & 3)) << 3)];
    };

    f32x4 acc[8][4];
    #pragma unroll
    for (int i = 0; i < 8; ++i)
        #pragma unroll
        for (int j = 0; j < 4; ++j) acc[i][j] = (f32x4){0.f,0.f,0.f,0.f};

    const int NT = K >> 5;
    stage4(0, 0, 0); stage4(0, 0, 1);

    for (int t = 0; t < NT; ++t) {
        const int cur = t & 1;
        VMCNT(0); SBAR;
        bf16x8 b_h[4], b_l[4];
        #pragma unroll
        for (int p = 0; p < 4; ++p) {
            bf16x8 a_h[2], a_l[2];
            if (p == 0) {
                #pragma unroll
                for (int j = 0; j < 4; ++j) {
                    int row = wn*64 + j*16 + fr;
                    b_h[j] = rd(Bh[cur], row, kc);
                    b_l[j] = rd(Bl[cur], row, kc);
                }
            }
            #pragma unroll
            for (int e = 0; e < 2; ++e) {
                int row = wm*128 + (p*2 + e)*16 + fr;
                a_h[e] = rd(Ah[cur], row, kc);
                a_l[e] = rd(Al[cur], row, kc);
            }
            if (p < 2 && t + 1 < NT) stage4((t+1) << 5, cur ^ 1, p);
            SBAR;
            __builtin_amdgcn_s_setprio(1);
            #pragma unroll
            for (int e = 0; e < 2; ++e)
                #pragma unroll
                for (int j = 0; j < 4; ++j) {
                    acc[p*2+e][j] = MFMA_BF16(a_h[e], b_h[j], acc[p*2+e][j], 0, 0, 0);
                    acc[p*2+e][j] = MFMA_BF16(a_h[e], b_l[j], acc[p*2+e][j], 0, 0, 0);
                    acc[p*2+e][j] = MFMA_BF16(a_l[e], b_h[j], acc[p*2+e][j], 0, 0, 0);
                }
            __builtin_amdgcn_s_setprio(0);
            SBAR;
        }
    }

    const i64 cbase = (i64)z2*cb2;
    if (OUT == 1) {
        ushort* C = (ushort*)Cp.p[z1];
        const int cfg = cmode.v[z1];
        const int tr = cfg >> 30;
        const i64 ldv = cfg & 0x3FFFFFFF;
        #pragma unroll
        for (int i = 0; i < 8; ++i)
            #pragma unroll
            for (int j = 0; j < 4; ++j)
                #pragma unroll
                for (int r = 0; r < 4; ++r) {
                    int m = m0 + wm*128 + i*16 + kc*4 + r;
                    int n = n0 + wn*64 + j*16 + fr;
                    ushort h, l; split1(acc[i][j][r], h, l);
                    i64 off = cbase + (tr ? (i64)n*ldv + m : (i64)m*ldv + n);
                    C[off] = h; C[off + cLo] = l;
                }
    } else {
        __half* C = (__half*)Cp.p[z1];
        float ls = 0.f, lq = 0.f;
        #pragma unroll
        for (int i = 0; i < 8; ++i)
            #pragma unroll
            for (int j = 0; j < 4; ++j)
                #pragma unroll
                for (int r = 0; r < 4; ++r) {
                    int m = m0 + wm*128 + i*16 + kc*4 + r;
                    int n = n0 + wn*64 + j*16 + fr;
                    float v = acc[i][j][r];
                    ls += v; lq += v*v;
                    C[cbase + (i64)m*cld + n] = __float2half(v);
                }
        #pragma unroll
        for (int off = 32; off; off >>= 1) { ls += __shfl_xor(ls, off); lq += __shfl_xor(lq, off); }
        if (lane == 0) { sred[wid] = ls; qred[wid] = lq; }
        __syncthreads();
        if (tid == 0) {
            float s = 0.f, qq = 0.f;
            #pragma unroll
            for (int w = 0; w < 8; ++w) { s += sred[w]; qq += qred[w]; }
            atomicAdd(&stats[2*z],   s);
            atomicAdd(&stats[2*z+1], qq);
        }
    }
}

// ---------------- TMx128-tile GEMM on pre-split planes, bf16x3, counted vmcnt ----
// SWZ=1: XCD-chunked 1D decode (z-inner ci).  SWZ=0: plain decode (x inner; ci unused).
template<int TM, int OUT, int SWZ>
__global__ __launch_bounds__(256) void gemm_ps(
    P4 Ap, P4 Bp, P4 Cp, I4 cmode, float* __restrict__ stats,
    int K, int zdiv, int ci, int Y, int X,
    i64 ab2, i64 alda, i64 aLo,
    i64 bb2, i64 bldb, i64 bLo,
    i64 cb2, i64 cld, i64 cLo)
{
    constexpr int CW = (TM == 128) ? 64 : 32;
    constexpr int FJ = CW / 16;
    __shared__ ushort Ah[2][TM*32], Al[2][TM*32];
    __shared__ ushort Bh[2][4096], Bl[2][4096];
    __shared__ float sred[4], qred[4];
    int x, y, z;
    if (SWZ) {
        const int q8 = gridDim.x >> 3;
        int wg = (blockIdx.x & 7) * q8 + (blockIdx.x >> 3);
        const int z2i = wg % ci; wg /= ci;
        y = wg % Y;    wg /= Y;
        x = wg % X;
        z = (wg / X)*ci + z2i;
    } else {
        int wg = blockIdx.x;
        x = wg % X;
        y = (wg / X) % Y;
        z = wg / (X * Y);
    }
    const int z1 = z / zdiv, z2 = z % zdiv;
    const int m0 = y*TM, n0 = x*128;

    const int tid = threadIdx.x, lane = tid & 63, wid = tid >> 6;
    const int wm = (TM == 128) ? (wid >> 1) : 0;
    const int wn = (TM == 128) ? (wid & 1) : wid;
    const int fr = lane & 15, kc = lane >> 4;
    const ushort* Aps = (const ushort*)Ap.p[z1] + (i64)z2*ab2 + (i64)m0*alda;
    const ushort* Bps = (const ushort*)Bp.p[z1] + (i64)z2*bb2 + (i64)n0*bldb;

    auto stageAB = [&](int k0, int pb){
        if constexpr (TM == 128) {
            #pragma unroll
            for (int q = 0; q < 2; ++q) {
                int r  = wid*32 + (lane >> 2) + q*16;
                int gs = (lane & 3) ^ ((r >> 1) & 3);
                const ushort* sa = Aps + (i64)r*alda + k0 + gs*8;
                glds16(sa,       &Ah[pb][(wid*32+q*16)*32]);
                glds16(sa + aLo, &Al[pb][(wid*32+q*16)*32]);
            }
        } else {
            int r  = wid*16 + (lane >> 2);
            int gs = (lane & 3) ^ ((r >> 1) & 3);
            const ushort* sa = Aps + (i64)r*alda + k0 + gs*8;
            glds16(sa,       &Ah[pb][(wid*16)*32]);
            glds16(sa + aLo, &Al[pb][(wid*16)*32]);
        }
        #pragma unroll
        for (int q = 0; q < 2; ++q) {
            int r  = wid*32 + (lane >> 2) + q*16;
            int gs = (lane & 3) ^ ((r >> 1) & 3);
            const ushort* sb = Bps + (i64)r*bldb + k0 + gs*8;
            glds16(sb,       &Bh[pb][(wid*32+q*16)*32]);
            glds16(sb + bLo, &Bl[pb][(wid*32+q*16)*32]);
        }
    };
    auto rd = [&](const ushort* P, int row, int kcc)->bf16x8 {
        return *(const bf16x8*)&P[row*32 + ((kcc ^ ((row >> 1) & 3)) << 3)];
    };

    f32x4 acc[4][FJ];
    #pragma unroll
    for (int i = 0; i < 4; ++i)
        #pragma unroll
        for (int j = 0; j < FJ; ++j) acc[i][j] = (f32x4){0.f,0.f,0.f,0.f};

    const int NT = K >> 5;
    stageAB(0, 0); stageAB(32, 1);

    for (int t = 0; t < NT; ++t) {
        const int cur = t & 1;
        if (t + 1 < NT) {
            if constexpr (TM == 128) { VMCNT(8); } else { VMCNT(6); }
        } else { VMCNT(0); }
        SBAR;
        bf16x8 a_h[4], a_l[4], b_h[FJ], b_l[FJ];
        #pragma unroll
        for (int i = 0; i < 4; ++i) {
            int row = wm*64 + i*16 + fr;
            a_h[i] = rd(Ah[cur], row, kc);
            a_l[i] = rd(Al[cur], row, kc);
        }
        #pragma unroll
        for (int j = 0; j < FJ; ++j) {
            int row = wn*CW + j*16 + fr;
            b_h[j] = rd(Bh[cur], row, kc);
            b_l[j] = rd(Bl[cur], row, kc);
        }
        __builtin_amdgcn_s_setprio(1);
        #pragma unroll
        for (int i = 0; i < 4; ++i)
            #pragma unroll
            for (int j = 0; j < FJ; ++j) {
                acc[i][j] = MFMA_BF16(a_h[i], b_h[j], acc[i][j], 0, 0, 0);
                acc[i][j] = MFMA_BF16(a_h[i], b_l[j], acc[i][j], 0, 0, 0);
                acc[i][j] = MFMA_BF16(a_l[i], b_h[j], acc[i][j], 0, 0, 0);
            }
        __builtin_amdgcn_s_setprio(0);
        LGKM0;
        SBAR;
        SCHED0;
        if (t + 2 < NT) stageAB((t+2) << 5, cur);
    }

    const i64 cbase = (i64)z2*cb2;
    if (OUT == 0) {
        float* C = (float*)Cp.p[z1];
        #pragma unroll
        for (int i = 0; i < 4; ++i)
            #pragma unroll
            for (int j = 0; j < FJ; ++j)
                #pragma unroll
                for (int r = 0; r < 4; ++r) {
                    int m = m0 + wm*64 + i*16 + kc*4 + r;
                    int n = n0 + wn*CW + j*16 + fr;
                    C[cbase + (i64)m*cld + n] = acc[i][j][r];
                }
    } else if (OUT == 1) {
        ushort* C = (ushort*)Cp.p[z1];
        const int cfg = cmode.v[z1];
        const int tr = cfg >> 30;
        const i64 ldv = cfg & 0x3FFFFFFF;
        #pragma unroll
        for (int i = 0; i < 4; ++i)
            #pragma unroll
            for (int j = 0; j < FJ; ++j)
                #pragma unroll
                for (int r = 0; r < 4; ++r) {
                    int m = m0 + wm*64 + i*16 + kc*4 + r;
                    int n = n0 + wn*CW + j*16 + fr;
                    ushort h, l; split1(acc[i][j][r], h, l);
                    i64 off = cbase + (tr ? (i64)n*ldv + m : (i64)m*ldv + n);
                    C[off] = h; C[off + cLo] = l;
                }
    } else if (OUT == 2) {
        __half* C = (__half*)Cp.p[z1];
        float ls = 0.f, lq = 0.f;
        #pragma unroll
        for (int i = 0; i < 4; ++i)
            #pragma unroll
            for (int j = 0; j < FJ; ++j)
                #pragma unroll
                for (int r = 0; r < 4; ++r) {
                    int m = m0 + wm*64 + i*16 + kc*4 + r;
                    int n = n0 + wn*CW + j*16 + fr;
                    float v = acc[i][j][r];
                    ls += v; lq += v*v;
                    C[cbase + (i64)m*cld + n] = __float2half(v);
                }
        #pragma unroll
        for (int off = 32; off; off >>= 1) { ls += __shfl_xor(ls, off); lq += __shfl_xor(lq, off); }
        if (lane == 0) { sred[wid] = ls; qred[wid] = lq; }
        __syncthreads();
        if (tid == 0) {
            atomicAdd(&stats[2*z],   sred[0]+sred[1]+sred[2]+sred[3]);
            atomicAdd(&stats[2*z+1], qred[0]+qred[1]+qred[2]+qred[3]);
        }
    } else {
        ushort* C = (ushort*)Cp.p[z1];
        #pragma unroll
        for (int i = 0; i < 4; ++i)
            #pragma unroll
            for (int j = 0; j < FJ; ++j)
                #pragma unroll
                for (int r = 0; r < 4; ++r) {
                    int m = m0 + wm*64 + i*16 + kc*4 + r;
                    int n = n0 + wn*CW + j*16 + fr;
                    ushort h, l; split1(acc[i][j][r], h, l);
                    i64 off = cbase + ((i64)(m >> 9) << 18) + ((i64)n << 9) + (m & 511);
                    C[off] = h; C[off + cLo] = l;
                }
    }
}

// ---------------- channel softmax: fp16 scores in -> sim bf16 hi/lo planes out ----
__global__ __launch_bounds__(256) void softmax_rows(
    __half* __restrict__ attn, ushort* __restrict__ lo,
    const float* __restrict__ stats, int rows_per_stat, float inv_count)
{
    const int ROWLEN = 2048;
    const int row = blockIdx.x;
    const int sidx = row / rows_per_stat;
    float sm = stats[2*sidx], sq = stats[2*sidx+1];
    float mean = sm * inv_count;
    float var = fmaxf(sq * inv_count - mean*mean, 0.f);
    float scale = rsqrtf(var + 1e-5f);
    __half* rp = attn + (i64)row * ROWLEN;
    ushort* hp = (ushort*)rp;
    ushort* lp = lo + (i64)row * ROWLEN;
    const int tid = threadIdx.x;
    float v[8]; float mx = -3.4e38f;
    #pragma unroll
    for (int s = 0; s < 8; ++s) { float x = __half2float(rp[tid + s*256]) * scale; v[s] = x; mx = fmaxf(mx, x); }
    #pragma unroll
    for (int off = 32; off; off >>= 1) mx = fmaxf(mx, __shfl_xor(mx, off));
    __shared__ float red[4];
    if ((tid & 63) == 0) red[tid >> 6] = mx;
    __syncthreads();
    mx = fmaxf(fmaxf(red[0], red[1]), fmaxf(red[2], red[3]));
    float ls = 0.f;
    #pragma unroll
    for (int s = 0; s < 8; ++s) { float e = __expf(v[s] - mx); v[s] = e; ls += e; }
    #pragma unroll
    for (int off = 32; off; off >>= 1) ls += __shfl_xor(ls, off);
    __syncthreads();
    if ((tid & 63) == 0) red[tid >> 6] = ls;
    __syncthreads();
    float inv = 1.f / (red[0] + red[1] + red[2] + red[3]);
    #pragma unroll
    for (int s = 0; s < 8; ++s) {
        ushort h, l; split1(v[s] * inv, h, l);
        hp[tid + s*256] = h; lp[tid + s*256] = l;
    }
}

// ---------------- 64x64 Gram partials + column sums over 256 rows (planes input) ----------------
__global__ __launch_bounds__(256) void gram64(
    const ushort* __restrict__ hi, i64 loOff, float* __restrict__ parts,
    i64 bstride, i64 zs2)
{
    __shared__ float T[16][68];
    __shared__ float csred[4][64];
    const int z = blockIdx.x;
    const int tid = threadIdx.x;
    const ushort* base = hi + (i64)(z>>3)*bstride + (i64)blockIdx.z*zs2
                       + (i64)blockIdx.y*256*512 + (z&7)*64;
    float g[4][4] = {{0.f}};
    float cs = 0.f;
    const int sr = tid >> 4, sc = (tid & 15) * 4;
    const int col = tid & 63, qq = tid >> 6;
    for (int grp = 0; grp < 16; ++grp) {
        i64 idx = (i64)(grp*16 + sr)*512 + sc;
        ushort4 hv = *(const ushort4*)&base[idx];
        ushort4 lv = *(const ushort4*)&base[loOff + idx];
        float4 ld;
        ld.x = bfpair(hv.x, lv.x); ld.y = bfpair(hv.y, lv.y);
        ld.z = bfpair(hv.z, lv.z); ld.w = bfpair(hv.w, lv.w);
        __syncthreads();
        *(float4*)&T[sr][sc] = ld;
        __syncthreads();
        #pragma unroll
        for (int rr = 0; rr < 16; ++rr) {
            const float4 a = *(const float4*)&T[rr][sr*4];
            const float4 b = *(const float4*)&T[rr][sc];
            g[0][0]+=a.x*b.x; g[0][1]+=a.x*b.y; g[0][2]+=a.x*b.z; g[0][3]+=a.x*b.w;
            g[1][0]+=a.y*b.x; g[1][1]+=a.y*b.y; g[1][2]+=a.y*b.z; g[1][3]+=a.y*b.w;
            g[2][0]+=a.z*b.x; g[2][1]+=a.z*b.y; g[2][2]+=a.z*b.z; g[2][3]+=a.z*b.w;
            g[3][0]+=a.w*b.x; g[3][1]+=a.w*b.y; g[3][2]+=a.w*b.z; g[3][3]+=a.w*b.w;
        }
        cs += T[qq*4+0][col] + T[qq*4+1][col] + T[qq*4+2][col] + T[qq*4+3][col];
    }
    float* outp = parts + (i64)((blockIdx.z*gridDim.y + blockIdx.y)*gridDim.x + blockIdx.x)*4160;
    #pragma unroll
    for (int xx = 0; xx < 4; ++xx)
        #pragma unroll
        for (int yy = 0; yy < 4; ++yy)
            outp[(sr*4+xx)*64 + sc + yy] = g[xx][yy];
    csred[qq][col] = cs;
    __syncthreads();
    if (tid < 64) outp[4096 + tid] = csred[0][tid]+csred[1][tid]+csred[2][tid]+csred[3][tid];
}

// scale/shift per (s,z): S1 = qbar.kbar, S2 = <G_Q, G_K>_F
__global__ __launch_bounds__(256) void fin_stats(
    const float* __restrict__ gq, const float* __restrict__ gk,
    float* __restrict__ ss)
{
    const int z = blockIdx.x, s = blockIdx.y;
    const int tid = threadIdx.x;
    const int lane = tid & 63, wid = tid >> 6;
    const float* q0 = gq + (i64)((s*2+0)*32 + z)*4160;
    const float* q1 = gq + (i64)((s*2+1)*32 + z)*4160;
    float p2 = 0.f;
    for (int i = tid; i < 4096; i += 256) {
        float a = q0[i] + q1[i];
        float b = 0.f;
        #pragma unroll
        for (int c = 0; c < 8; ++c) b += gk[(i64)(c*32 + z)*4160 + i];
        p2 += a*b;
    }
    float p1 = 0.f;
    if (tid < 64) {
        float a = q0[4096+tid] + q1[4096+tid];
        float b = 0.f;
        #pragma unroll
        for (int c = 0; c < 8; ++c) b += gk[(i64)(c*32 + z)*4160 + 4096 + tid];
        p1 = a*b;
    }
    #pragma unroll
    for (int off = 32; off; off >>= 1) { p2 += __shfl_xor(p2, off); p1 += __shfl_xor(p1, off); }
    __shared__ float r2[4], r1[4];
    if (lane == 0) { r2[wid] = p2; r1[wid] = p1; }
    __syncthreads();
    if (tid == 0) {
        float S2 = r2[0]+r2[1]+r2[2]+r2[3];
        float S1 = r1[0]+r1[1]+r1[2]+r1[3];
        const float inv = 1.f/1048576.f;
        float mu = S1*inv;
        float var = fmaxf(S2*inv - mu*mu, 0.f);
        float sc = rsqrtf(var + 1e-5f);
        ss[(s*32+z)*2] = sc;
        ss[(s*32+z)*2+1] = sc*mu;
    }
}

// ---------------- fused spatial flash attention: swapped QK^T, vectorized P ----
// XCD-swizzled 1D decode (qt-blocks of one (zz,s) co-located on an XCD).
__global__ __launch_bounds__(256) void flash_ps(
    const ushort* __restrict__ Qp, const ushort* __restrict__ Kp,
    const ushort* __restrict__ Vtp, const float* __restrict__ ss,
    ushort* __restrict__ ctxp)
{
    __shared__ ushort Ph[4096], Pl[4096];          // Q in prologue, P [q][kv] in loop
    __shared__ ushort Kh[2][4096], Kl[2][4096];
    __shared__ ushort Vh[2][4096], Vl[2][4096];
    const int q8g = gridDim.x >> 3;
    int wg = (blockIdx.x & 7) * q8g + (blockIdx.x >> 3);
    const int qt = wg & 7, zz = (wg >> 3) & 31, s = wg >> 8;
    const int b = zz >> 3, hD = (zz & 7) * 64;
    const float scale = ss[(s*32+zz)*2], shift = ss[(s*32+zz)*2+1];
    const ushort* Qb = Qp + (i64)s*2097152 + (i64)b*262144 + (i64)(qt*64)*512 + hD;
    const ushort* Kb = Kp + (i64)b*1048576 + hD;
    const ushort* Vb = Vtp + (i64)b*1048576 + (i64)hD*2048;
    const int tid = threadIdx.x, lane = tid & 63, wid = tid >> 6;
    const int fr = lane & 15, kc = lane >> 4;
    const int wkv = wid >> 1, wq2 = wid & 1;       // QK^T wave roles
    const int wq3 = wid >> 1, wd  = wid & 1;       // PV wave roles

    auto stage64 = [&](const ushort* src, i64 ld, i64 lo, ushort* Lh, ushort* Ll){
        #pragma unroll
        for (int q = 0; q < 2; ++q) {
            int rb = wid*16 + q*8;
            int r = rb + (lane >> 3);
            int gs = (lane & 7) ^ (r & 7);
            const ushort* p = src + (i64)r*ld + gs*8;
            glds16(p,      &Lh[rb*64]);
            glds16(p + lo, &Ll[rb*64]);
        }
    };

    stage64(Qb, 512, 1048576, Ph, Pl);
    stage64(Kb, 512, 4194304, Kh[0], Kl[0]);
    stage64(Vb, 2048, 4194304, Vh[0], Vl[0]);
    VMCNT(8); SBAR;
    bf16x8 qh[2][2], ql[2][2];
    #pragma unroll
    for (int j = 0; j < 2; ++j)
        #pragma unroll
        for (int ks = 0; ks < 2; ++ks) {
            int row = wq2*32 + j*16 + fr;
            qh[j][ks] = fragS(Ph, row, ks*4 + kc);
            ql[j][ks] = fragS(Pl, row, ks*4 + kc);
        }
    LGKM0; SBAR;
    SCHED0;
    stage64(Kb + (i64)64*512, 512, 4194304, Kh[1], Kl[1]);
    stage64(Vb + 64, 2048, 4194304, Vh[1], Vl[1]);

    f32x4 ctx[2][2];
    #pragma unroll
    for (int i = 0; i < 2; ++i)
        #pragma unroll
        for (int j = 0; j < 2; ++j) ctx[i][j] = (f32x4){0.f,0.f,0.f,0.f};
    float dl[2] = {0.f, 0.f};

    for (int t = 0; t < 32; ++t) {
        const int cur = t & 1;
        if (t < 31) { VMCNT(8); } else { VMCNT(0); }
        SBAR;
        f32x4 sacc[2][2];
        #pragma unroll
        for (int i = 0; i < 2; ++i)
            #pragma unroll
            for (int j = 0; j < 2; ++j) sacc[i][j] = (f32x4){0.f,0.f,0.f,0.f};
        #pragma unroll
        for (int ks = 0; ks < 2; ++ks) {
            bf16x8 khf[2], klf[2];
            #pragma unroll
            for (int i = 0; i < 2; ++i) {
                int row = wkv*32 + i*16 + fr;
                khf[i] = fragS(Kh[cur], row, ks*4 + kc);
                klf[i] = fragS(Kl[cur], row, ks*4 + kc);
            }
            __builtin_amdgcn_s_setprio(1);
            #pragma unroll
            for (int i = 0; i < 2; ++i)
                #pragma unroll
                for (int j = 0; j < 2; ++j) {
                    sacc[i][j] = MFMA_BF16(khf[i], qh[j][ks], sacc[i][j], 0, 0, 0);
                    sacc[i][j] = MFMA_BF16(khf[i], ql[j][ks], sacc[i][j], 0, 0, 0);
                    sacc[i][j] = MFMA_BF16(klf[i], qh[j][ks], sacc[i][j], 0, 0, 0);
                }
            __builtin_amdgcn_s_setprio(0);
        }
        #pragma unroll
        for (int i = 0; i < 2; ++i)
            #pragma unroll
            for (int j = 0; j < 2; ++j) {
                ushort h4[4], l4[4];
                #pragma unroll
                for (int r = 0; r < 4; ++r) {
                    float p = __expf(sacc[i][j][r]*scale - shift);
                    dl[j] += p;
                    split1(p, h4[r], l4[r]);
                }
                int q = wq2*32 + j*16 + fr;
                int oct = wkv*4 + i*2 + (kc >> 1);
                int ad = q*64 + ((oct ^ (q & 7)) << 3) + ((kc & 1) << 2);
                *(ushort4*)&Ph[ad] = make_ushort4(h4[0],h4[1],h4[2],h4[3]);
                *(ushort4*)&Pl[ad] = make_ushort4(l4[0],l4[1],l4[2],l4[3]);
            }
        LGKM0; SBAR;
        SCHED0;
        if (t < 30) stage64(Kb + (i64)((t+2)*64)*512, 512, 4194304, Kh[cur], Kl[cur]);
        #pragma unroll
        for (int ks = 0; ks < 2; ++ks) {
            bf16x8 vhf[2], vlf[2], pah[2], pal[2];
            #pragma unroll
            for (int j = 0; j < 2; ++j) {
                int row = wd*32 + j*16 + fr;
                vhf[j] = fragS(Vh[cur], row, ks*4 + kc);
                vlf[j] = fragS(Vl[cur], row, ks*4 + kc);
            }
            #pragma unroll
            for (int i = 0; i < 2; ++i) {
                int q = wq3*32 + i*16 + fr;
                int o = ks*4 + kc;
                pah[i] = *(const bf16x8*)&Ph[q*64 + ((o ^ (q & 7)) << 3)];
                pal[i] = *(const bf16x8*)&Pl[q*64 + ((o ^ (q & 7)) << 3)];
            }
            __builtin_amdgcn_s_setprio(1);
            #pragma unroll
            for (int i = 0; i < 2; ++i)
                #pragma unroll
                for (int j = 0; j < 2; ++j) {
                    ctx[i][j] = MFMA_BF16(pah[i], vhf[j], ctx[i][j], 0, 0, 0);
                    ctx[i][j] = MFMA_BF16(pah[i], vlf[j], ctx[i][j], 0, 0, 0);
                    ctx[i][j] = MFMA_BF16(pal[i], vhf[j], ctx[i][j], 0, 0, 0);
                }
            __builtin_amdgcn_s_setprio(0);
        }
        LGKM0; SBAR;
        SCHED0;
        if (t < 30) stage64(Vb + (t+2)*64, 2048, 4194304, Vh[cur], Vl[cur]);
    }

    float* denf = (float*)Pl;
    #pragma unroll
    for (int j = 0; j < 2; ++j) {
        float d = dl[j];
        d += __shfl_xor(d, 16); d += __shfl_xor(d, 32);
        if (kc == 0) denf[wkv*64 + wq2*32 + j*16 + fr] = d;
    }
    __syncthreads();
    ushort* Cb = ctxp + (i64)s*2097152 + (i64)b*262144;
    #pragma unroll
    for (int i = 0; i < 2; ++i)
        #pragma unroll
        for (int j = 0; j < 2; ++j)
            #pragma unroll
            for (int r = 0; r < 4; ++r) {
                int row = wq3*32 + i*16 + kc*4 + r;
                int col = wd*32 + j*16 + fr;
                float dv = denf[row] + denf[64 + row];
                ushort h, l; split1(ctx[i][j][r] / dv, h, l);
                i64 off = (i64)(qt*64 + row)*512 + hD + col;
                Cb[off] = h; Cb[off + 1048576] = l;
            }
}

static inline P4 p4x(const void* a, const void* b, const void* c, const void* d){
    P4 x; x.p[0]=a; x.p[1]=b; x.p[2]=c; x.p[3]=d; return x;
}
static inline P4 p4x(const void* a){ return p4x(a,a,a,a); }
static inline I4 i4x(int a, int b, int c, int d){ I4 x; x.v[0]=a; x.v[1]=b; x.v[2]=c; x.v[3]=d; return x; }
#define TRC(ld) ((1<<30)|(ld))   // transposed plane store with leading dim ld

extern "C" void kernel_launch(void* const* d_in, const int* in_sizes, int n_in,
                              void* d_out, int out_size, void* d_ws, size_t ws_size,
                              hipStream_t stream)
{
    (void)in_sizes; (void)n_in; (void)out_size;
    const float* emb[4] = {(const float*)d_in[0], (const float*)d_in[1],
                           (const float*)d_in[2], (const float*)d_in[3]};
    const float* embC = (const float*)d_in[4];
    const float* Wq[4] = {(const float*)d_in[5], (const float*)d_in[6],
                          (const float*)d_in[7], (const float*)d_in[8]};
    const float* Wk  = (const float*)d_in[9];
    const float* Wv  = (const float*)d_in[10];
    const float* WqC = (const float*)d_in[11];
    const float* WkC = (const float*)d_in[12];
    const float* WvC = (const float*)d_in[13];
    const float* Wo[4] = {(const float*)d_in[14], (const float*)d_in[15],
                          (const float*)d_in[16], (const float*)d_in[17]};
    float* out = (float*)d_out;

    char* ws = (char*)d_ws;
    const size_t MB = 1024*1024;
    if (ws_size < 128*MB + 512) return;
    auto U = [&](size_t mb){ return (ushort*)(ws + mb*MB); };
    float* stats = (float*)(ws + 122*MB);
    float* ssbuf = (float*)(ws + 122*MB + 1024);
    float* GKp   = (float*)(ws + 48*MB);
    float* GQp   = (float*)(ws + 53*MB);
    __half* scores = (__half*)(ws + 16*MB);

    hipMemsetAsync(stats, 0, 512, stream);

    // ---- pre-split embC + all weights ----
    {
        PSJobs J;
        const float* srcs[13] = {embC, WqC, WkC, WvC, Wk, Wv,
                                 Wq[0],Wq[1],Wq[2],Wq[3], Wo[0],Wo[1],Wo[2]};
        ushort* dsts[13] = {U(0),U(16),U(32),U(48),U(64),U(65),
                            U(66),U(67),U(68),U(69), U(70),U(71),U(72)};
        int blks[13] = {2048,2048,2048,2048,128,128, 128,128,128,128, 128,128,128};
        int a = 0;
        for (int j = 0; j < 13; ++j) { J.s[j]=srcs[j]; J.d[j]=dsts[j]; J.st[j]=a; a+=blks[j]; }
        J.st[13] = a;
        presplit<<<dim3(a), 256, 0, stream>>>(J);
    }
    // ---- channel projections: PLAIN-decode gemm_ps (r13-measured best 209.8us) ----
    gemm_ps<128,1,0><<<dim3(768), 256, 0, stream>>>(
        p4x(U(0)), p4x(U(16), U(32), U(48), U(48)), p4x(U(74), U(90), U(106), U(106)),
        i4x(TRC(512), TRC(512), 2048, 2048), nullptr,
        2048, 4, 1, 4, 16,
        1048576, 2048, 4194304,   0, 2048, 4194304,   1048576, 0, 4194304);
    // ---- pre-split emb1..4 + Wo[3] ----
    {
        PSJobs J;
        const float* srcs[13] = {emb[0], emb[1], emb[2], emb[3], Wo[3],
                                 nullptr,nullptr,nullptr,nullptr,nullptr,nullptr,nullptr,nullptr};
        ushort* dsts[13] = {U(0), U(4), U(8), U(12), U(73),
                            nullptr,nullptr,nullptr,nullptr,nullptr,nullptr,nullptr,nullptr};
        int blks[5] = {512,512,512,512,128};
        int a = 0;
        for (int j = 0; j < 5; ++j) { J.s[j]=srcs[j]; J.d[j]=dsts[j]; J.st[j]=a; a+=blks[j]; }
        for (int j = 5; j < 14; ++j) J.st[j] = a;
        presplit<<<dim3(a), 256, 0, stream>>>(J);
    }
    // ---- attn_c: 8-phase 256^2; grid 256 exact (r12 config) ----
    gemm_8p<2><<<dim3(256), 512, 0, stream>>>(
        p4x(U(74)), p4x(U(90)), p4x(scores), i4x(0,0,0,0), stats,
        512, 4, 1, 8, 8,
        1048576, 512, 4194304,   1048576, 512, 4194304,   4194304, 2048, 0);
    softmax_rows<<<dim3(4*2048), 256, 0, stream>>>(scores, U(74), stats, 2048, 1.f/4194304.f);
    // ---- ctx_c: TM=64 swizzled grid 512 (r12 config) ----
    gemm_ps<64,3,1><<<dim3(512), 256, 0, stream>>>(
        p4x(U(16)), p4x(U(106)), p4x(U(48)), i4x(0,0,0,0), nullptr,
        2048, 4, 1, 32, 4,
        4194304, 2048, 30408704,   1048576, 2048, 4194304,   1048576, 0, 4194304);
    // ---- K/V projections: TM=128 swizzled grid 512 (r12 config) ----
    gemm_ps<128,1,1><<<dim3(512), 256, 0, stream>>>(
        p4x(U(48)), p4x(U(64), U(65), U(65), U(65)), p4x(U(74), U(90), U(90), U(90)),
        i4x(512, TRC(2048), 0, 0), nullptr,
        512, 4, 4, 16, 4,
        1048576, 512, 4194304,   0, 512, 262144,   1048576, 0, 4194304);
    // ---- Q projections: TM=64 swizzled grid 512 (r12 config) ----
    gemm_ps<64,1,1><<<dim3(512), 256, 0, stream>>>(
        p4x(U(0), U(4), U(8), U(12)), p4x(U(66), U(67), U(68), U(69)),
        p4x(U(106), U(110), U(114), U(118)),
        i4x(512,512,512,512), nullptr,
        512, 4, 4, 8, 4,
        262144, 512, 1048576,   0, 512, 262144,   262144, 0, 1048576);
    // ---- Gram stats + finalize ----
    gram64<<<dim3(32, 8, 1), 256, 0, stream>>>(U(74), 4194304, GKp, 1048576, 0);
    gram64<<<dim3(32, 2, 4), 256, 0, stream>>>(U(106), 1048576, GQp, 262144, 2097152);
    fin_stats<<<dim3(32, 4), 256, 0, stream>>>(GQp, GKp, ssbuf);
    // ---- fused spatial attention (swapped QK^T, XCD-swizzled, r12 config) ----
    flash_ps<<<dim3(1024), 256, 0, stream>>>(U(106), U(74), U(90), ssbuf, U(16));
    // ---- output projections: TM=64 swizzled grid 512 (r12 config) ----
    gemm_ps<64,0,1><<<dim3(512), 256, 0, stream>>>(
        p4x(U(16), U(20), U(24), U(28)), p4x(U(70), U(71), U(72), U(73)),
        p4x(out, out + 1048576, out + 2097152, out + 3145728),
        i4x(0,0,0,0), nullptr,
        512, 4, 4, 8, 4,
        262144, 512, 1048576,   0, 512, 262144,   262144, 512, 1048576);
}